// Round 5
// baseline (120.946 us; speedup 1.0000x reference)
//
#include <hip/hip_runtime.h>
#include <hip/hip_bf16.h>

typedef short bf16x8 __attribute__((ext_vector_type(8)));
typedef float f32x16 __attribute__((ext_vector_type(16)));
typedef float f32x2  __attribute__((ext_vector_type(2)));

#define S 2048
#define D 64
#define NBH 24

__device__ __forceinline__ int cvtpk_bf16(float lo, float hi) {
    int r;
    asm("v_cvt_pk_bf16_f32 %0, %1, %2" : "=v"(r) : "v"(lo), "v"(hi));
    return r;
}
__device__ __forceinline__ f32x2 pk_fma(f32x2 a, f32x2 b, f32x2 c) {
    f32x2 d;
    asm("v_pk_fma_f32 %0, %1, %2, %3" : "=v"(d) : "v"(a), "v"(b), "v"(c));
    return d;
}
__device__ __forceinline__ f32x2 pk_mul(f32x2 a, f32x2 b) {
    f32x2 d;
    asm("v_pk_mul_f32 %0, %1, %2" : "=v"(d) : "v"(a), "v"(b));
    return d;
}
__device__ __forceinline__ f32x2 pk_add(f32x2 a, f32x2 b) {
    f32x2 d;
    asm("v_pk_add_f32 %0, %1, %2" : "=v"(d) : "v"(a), "v"(b));
    return d;
}

// Fused prep: L2-normalize Q,K rows (fp32->bf16) + transpose V with key-mask fold.
__global__ __launch_bounds__(256) void prep(const float* __restrict__ Q,
                                            const float* __restrict__ K,
                                            const float* __restrict__ V,
                                            const int* __restrict__ mask,
                                            __hip_bfloat16* __restrict__ Qn,
                                            __hip_bfloat16* __restrict__ Kn,
                                            __hip_bfloat16* __restrict__ Vt) {
    __shared__ float tile[64][65];
    const int NB = NBH * S / 4;               // 12288 blocks per tensor
    int blk = blockIdx.x;
    if (blk < 2 * NB) {
        int half = blk >= NB;
        int row  = (blk - half * NB) * 4 + (threadIdx.x >> 6);
        int lane = threadIdx.x & 63;
        const float* in = half ? K : Q;
        __hip_bfloat16* out = half ? Kn : Qn;
        float x = in[(size_t)row * 64 + lane];
        float ss = x * x;
        #pragma unroll
        for (int m = 1; m <= 32; m <<= 1) ss += __shfl_xor(ss, m, 64);
        out[(size_t)row * 64 + lane] = __float2bfloat16(x * rsqrtf(ss + 1e-6f));
        return;
    }
    blk -= 2 * NB;                            // 768 transpose blocks
    int bh = blk >> 5;
    int b  = bh / 12;
    int s0 = (blk & 31) << 6;
    int t  = threadIdx.x;
    #pragma unroll
    for (int i = 0; i < 16; ++i) {
        int idx = i * 256 + t;
        int sl = idx >> 6, d = idx & 63;
        float mv = (float)mask[b * S + s0 + sl];
        tile[sl][d] = V[(size_t)bh * S * D + (size_t)(s0 + sl) * D + d] * mv;
    }
    __syncthreads();
    #pragma unroll
    for (int i = 0; i < 16; ++i) {
        int idx = i * 256 + t;
        int d = idx >> 6, sl = idx & 63;
        Vt[(size_t)bh * S * D + (size_t)d * S + s0 + sl] = __float2bfloat16(tile[sl][d]);
    }
}

// Main: fully wave-independent, no LDS, no barriers. Each wave: (bh, 32 q-rows,
// key-range). K/V fragments direct global->VGPR (L1 absorbs the stride-128B walk),
// A/B double-buffered. PARTIAL: key-half per wave, raw partials out (3072 waves).
// else: full keys, fused mask+normalize (1536 waves).
template<bool PARTIAL>
__global__ __launch_bounds__(256) void yoso_main(const __hip_bfloat16* __restrict__ Qn,
                                                 const __hip_bfloat16* __restrict__ Kn,
                                                 const __hip_bfloat16* __restrict__ Vt,
                                                 const int* __restrict__ mask,
                                                 const int* __restrict__ hlen_ptr,
                                                 float* __restrict__ outp) {
    const int gid  = blockIdx.x * 4 + (threadIdx.x >> 6);
    int bh, q0, kh;
    if (PARTIAL) { bh = gid >> 7; q0 = ((gid >> 1) & 63) << 5; kh = gid & 1; }
    else         { bh = gid >> 6; q0 = (gid & 63) << 5;        kh = 0; }
    const int NTt = PARTIAL ? 32 : 64;        // 32-key tiles
    const int kbase = kh << 10;

    const int b    = bh / 12;
    const int lane = threadIdx.x & 63;
    const int h    = lane >> 5;
    const int c31  = lane & 31;
    const int hcode = hlen_ptr[0];
    const size_t head = (size_t)bh * S * D;

    // Q B-fragments (held all loop): B[k=d][col=q], lane col = c31, d = 16kd+8h+j
    bf16x8 qf[4];
    {
        const __hip_bfloat16* qp = Qn + head + (size_t)(q0 + c31) * D + h * 8;
        qf[0] = *(const bf16x8*)(qp);
        qf[1] = *(const bf16x8*)(qp + 16);
        qf[2] = *(const bf16x8*)(qp + 32);
        qf[3] = *(const bf16x8*)(qp + 48);
    }

    // direct-load bases: K row (key) stride 128B, Vt row (d) stride 4096B
    const char* kp = (const char*)(Kn + head) + (kbase + c31) * 128 + 16 * h;
    const char* vp = (const char*)(Vt + head) + c31 * 4096 + kbase * 2 + 16 * h;

    const f32x16 z16 = {0,0,0,0,0,0,0,0,0,0,0,0,0,0,0,0};
    f32x16 xacc0 = z16, xacc1 = z16;

    const bool  p9 = (hcode == 9);
    const float hf = (float)hcode;
    // -q(z) coeffs (negated: tp = 0.5 + (-q)*sqrt(z)) and 0.5
    const f32x2 cq3 = {-0.00596128f, -0.00596128f};
    const f32x2 cq2 = {-0.00575336f, -0.00575336f};
    const f32x2 cq1 = {-0.03812704f, -0.03812704f};
    const f32x2 cq0 = {-0.4501324f,  -0.4501324f};
    const f32x2 chf = {0.5f, 0.5f};

    auto LOAD = [&](bf16x8 (&kf)[4], bf16x8 (&vf)[4], int t) {
        const char* k = kp + (size_t)t * 4096;   // 32 keys x 128B
        const char* v = vp + (size_t)t * 64;     // 32 keys x 2B
        #pragma unroll
        for (int kd = 0; kd < 4; ++kd) kf[kd] = *(const bf16x8*)(k + kd * 32);
        #pragma unroll
        for (int kb2 = 0; kb2 < 2; ++kb2) {
            vf[2 * kb2]     = *(const bf16x8*)(v + kb2 * 32);            // d 0..31
            vf[2 * kb2 + 1] = *(const bf16x8*)(v + 131072 + kb2 * 32);   // d 32..63
        }
    };

    auto COMPUTE = [&](bf16x8 (&kf)[4], bf16x8 (&vf)[4]) {
        // S^T = K @ Q^T : C[row=key][col=q]
        f32x16 sacc = __builtin_amdgcn_mfma_f32_32x32x16_bf16(kf[0], qf[0], z16, 0, 0, 0);
        #pragma unroll
        for (int kd = 1; kd < 4; ++kd)
            sacc = __builtin_amdgcn_mfma_f32_32x32x16_bf16(kf[kd], qf[kd], sacc, 0, 0, 0);

        // w = x^h, x = 0.5 + copysign(0.5 - sqrt(z)*q(z), s), z = 1-|s|  (packed f32)
        int u_[8];
        #pragma unroll
        for (int i = 0; i < 8; ++i) {
            f32x2 sv = { sacc[2 * i], sacc[2 * i + 1] };
            f32x2 zz = { fmaxf(1.0f - fabsf(sv.x), 0.0f),
                         fmaxf(1.0f - fabsf(sv.y), 0.0f) };
            f32x2 qq = pk_fma(cq3, zz, cq2);
            qq = pk_fma(qq, zz, cq1);
            qq = pk_fma(qq, zz, cq0);
            f32x2 rt = { __builtin_amdgcn_sqrtf(zz.x), __builtin_amdgcn_sqrtf(zz.y) };
            f32x2 tp = pk_fma(qq, rt, chf);              // 0.5 - q*sqrt(z)  (>= 0)
            f32x2 cs = { __builtin_copysignf(tp.x, sv.x),
                         __builtin_copysignf(tp.y, sv.y) };
            f32x2 xs = pk_add(cs, chf);                  // 0.5 + copysign(...)
            f32x2 wv;
            if (p9) {
                f32x2 x2 = pk_mul(xs, xs);
                f32x2 x4 = pk_mul(x2, x2);
                f32x2 x8 = pk_mul(x4, x4);
                wv = pk_mul(x8, xs);
            } else {
                wv.x = __builtin_amdgcn_exp2f(hf * __builtin_amdgcn_logf(xs.x));
                wv.y = __builtin_amdgcn_exp2f(hf * __builtin_amdgcn_logf(xs.y));
            }
            u_[i] = cvtpk_bf16(wv.x, wv.y);
        }
        asm("v_permlane32_swap_b32 %0, %1" : "+v"(u_[0]), "+v"(u_[2]));
        asm("v_permlane32_swap_b32 %0, %1" : "+v"(u_[1]), "+v"(u_[3]));
        asm("v_permlane32_swap_b32 %0, %1" : "+v"(u_[4]), "+v"(u_[6]));
        asm("v_permlane32_swap_b32 %0, %1" : "+v"(u_[5]), "+v"(u_[7]));
        union { int i[4]; bf16x8 v; } f0, f1;
        f0.i[0] = u_[0]; f0.i[1] = u_[1]; f0.i[2] = u_[2]; f0.i[3] = u_[3];
        f1.i[0] = u_[4]; f1.i[1] = u_[5]; f1.i[2] = u_[6]; f1.i[3] = u_[7];

        // X += P @ V
        xacc0 = __builtin_amdgcn_mfma_f32_32x32x16_bf16(f0.v, vf[0], xacc0, 0, 0, 0);
        xacc1 = __builtin_amdgcn_mfma_f32_32x32x16_bf16(f0.v, vf[1], xacc1, 0, 0, 0);
        xacc0 = __builtin_amdgcn_mfma_f32_32x32x16_bf16(f1.v, vf[2], xacc0, 0, 0, 0);
        xacc1 = __builtin_amdgcn_mfma_f32_32x32x16_bf16(f1.v, vf[3], xacc1, 0, 0, 0);
    };

    bf16x8 kfA[4], vfA[4], kfB[4], vfB[4];
    LOAD(kfA, vfA, 0);
    for (int t = 0; t < NTt; t += 2) {
        LOAD(kfB, vfB, t + 1);
        COMPUTE(kfA, vfA);
        if (t + 2 < NTt) LOAD(kfA, vfA, t + 2);
        COMPUTE(kfB, vfB);
    }

    // epilogue: store partials (PARTIAL) or fused mask+normalize
    #pragma unroll
    for (int r = 0; r < 16; ++r) {
        int q  = (r & 3) + 8 * (r >> 2) + 4 * h;
        int qg = q0 + q;
        if (PARTIAL) {
            float* pp = outp + ((size_t)(kh * NBH + bh) * S + qg) * D;
            pp[c31]      = xacc0[r];
            pp[32 + c31] = xacc1[r];
        } else {
            float mq = (float)mask[b * S + qg];
            float x0 = xacc0[r] * mq, x1 = xacc1[r] * mq;
            float ss = x0 * x0 + x1 * x1;
            #pragma unroll
            for (int m = 1; m <= 16; m <<= 1) ss += __shfl_xor(ss, m, 64);
            float sc = rsqrtf(ss + 1e-6f);
            float* op = outp + ((size_t)bh * S + qg) * D;
            op[c31]      = x0 * sc;
            op[32 + c31] = x1 * sc;
        }
    }
}

// Pass 2: sum key-half partials, apply query mask, L2-normalize, store fp32.
__global__ __launch_bounds__(256) void combine_norm(const float* __restrict__ P,
                                                    const int* __restrict__ mask,
                                                    float* __restrict__ out) {
    size_t row = (size_t)blockIdx.x * 4 + (threadIdx.x >> 6);
    int lane = threadIdx.x & 63;
    size_t i = row * 64 + lane;
    float x = P[i] + P[(size_t)NBH * S * D + i];
    int bh = (int)(row >> 11);          // S = 2048
    int sidx = (int)(row & 2047);
    int b = bh / 12;
    x *= (float)mask[b * S + sidx];
    float ss = x * x;
    #pragma unroll
    for (int m = 1; m <= 32; m <<= 1) ss += __shfl_xor(ss, m, 64);
    out[i] = x * rsqrtf(ss + 1e-6f);
}

extern "C" void kernel_launch(void* const* d_in, const int* in_sizes, int n_in,
                              void* d_out, int out_size, void* d_ws, size_t ws_size,
                              hipStream_t stream) {
    const float* Q    = (const float*)d_in[0];
    const float* K    = (const float*)d_in[1];
    const float* V    = (const float*)d_in[2];
    const int*   mask = (const int*)d_in[3];
    const int*   hlen = (const int*)d_in[4];
    float*       out  = (float*)d_out;

    __hip_bfloat16* Qn = (__hip_bfloat16*)d_ws;
    __hip_bfloat16* Kn = Qn + (size_t)NBH * S * D;
    __hip_bfloat16* Vt = Kn + (size_t)NBH * S * D;
    float* Pbuf = (float*)((char*)d_ws + 3ull * NBH * S * D * 2);  // 2x partials fp32

    const size_t ws_need = 3ull * NBH * S * D * 2 + 2ull * NBH * S * D * 4;

    prep<<<2 * NBH * S / 4 + NBH * 32, 256, 0, stream>>>(Q, K, V, mask, Qn, Kn, Vt);
    if (ws_size >= ws_need) {
        yoso_main<true><<<768, 256, 0, stream>>>(Qn, Kn, Vt, mask, hlen, Pbuf);
        combine_norm<<<NBH * S / 4, 256, 0, stream>>>(Pbuf, mask, out);
    } else {
        yoso_main<false><<<384, 256, 0, stream>>>(Qn, Kn, Vt, mask, hlen, out);
    }
}

// Round 6
// 84.821 us; speedup vs baseline: 1.4259x; 1.4259x over previous
//
#include <hip/hip_runtime.h>
#include <hip/hip_bf16.h>

typedef short bf16x8 __attribute__((ext_vector_type(8)));
typedef float f32x16 __attribute__((ext_vector_type(16)));
typedef float f32x2  __attribute__((ext_vector_type(2)));

#define S 2048
#define D 64
#define NBH 24

#define GLOAD16(g, l) __builtin_amdgcn_global_load_lds(                      \
    (const __attribute__((address_space(1))) unsigned int*)(g),              \
    (__attribute__((address_space(3))) unsigned int*)(l), 16, 0, 0)

__device__ __forceinline__ int cvtpk_bf16(float lo, float hi) {
    int r;
    asm("v_cvt_pk_bf16_f32 %0, %1, %2" : "=v"(r) : "v"(lo), "v"(hi));
    return r;
}
__device__ __forceinline__ f32x2 pk_fma(f32x2 a, f32x2 b, f32x2 c) {
    f32x2 d;
    asm("v_pk_fma_f32 %0, %1, %2, %3" : "=v"(d) : "v"(a), "v"(b), "v"(c));
    return d;
}
__device__ __forceinline__ f32x2 pk_mul(f32x2 a, f32x2 b) {
    f32x2 d;
    asm("v_pk_mul_f32 %0, %1, %2" : "=v"(d) : "v"(a), "v"(b));
    return d;
}
__device__ __forceinline__ f32x2 pk_add(f32x2 a, f32x2 b) {
    f32x2 d;
    asm("v_pk_add_f32 %0, %1, %2" : "=v"(d) : "v"(a), "v"(b));
    return d;
}

// Fused prep (float4-vectorized): L2-normalize Q,K rows (fp32->bf16) + transpose V
// with key-mask fold. Norm: 16 lanes x float4 per row, 16 rows/block.
__global__ __launch_bounds__(256) void prep(const float* __restrict__ Q,
                                            const float* __restrict__ K,
                                            const float* __restrict__ V,
                                            const int* __restrict__ mask,
                                            __hip_bfloat16* __restrict__ Qn,
                                            __hip_bfloat16* __restrict__ Kn,
                                            __hip_bfloat16* __restrict__ Vt) {
    __shared__ float tile[64][65];
    const int NBQK = 2 * NBH * S / 16;            // 6144 norm blocks
    int blk = blockIdx.x;
    int t = threadIdx.x;
    if (blk < NBQK) {
        int l16 = t & 15;
        int row = blk * 16 + (t >> 4);            // 0..98303
        int half = row >= NBH * S;
        const float* in = half ? K : Q;
        __hip_bfloat16* out = half ? Kn : Qn;
        row -= half * NBH * S;
        float4 x = *(const float4*)(in + (size_t)row * 64 + l16 * 4);
        float ss = x.x * x.x + x.y * x.y + x.z * x.z + x.w * x.w;
        #pragma unroll
        for (int m = 1; m <= 8; m <<= 1) ss += __shfl_xor(ss, m, 64);
        float sc = rsqrtf(ss + 1e-6f);
        int2 pk = { cvtpk_bf16(x.x * sc, x.y * sc), cvtpk_bf16(x.z * sc, x.w * sc) };
        *(int2*)(out + (size_t)row * 64 + l16 * 4) = pk;
        return;
    }
    blk -= NBQK;                                  // 768 transpose blocks
    int bh = blk >> 5;
    int b  = bh / 12;
    int s0 = (blk & 31) << 6;
    #pragma unroll
    for (int i = 0; i < 16; ++i) {
        int idx = i * 256 + t;
        int sl = idx >> 6, d = idx & 63;
        float mv = (float)mask[b * S + s0 + sl];
        tile[sl][d] = V[(size_t)bh * S * D + (size_t)(s0 + sl) * D + d] * mv;
    }
    __syncthreads();
    #pragma unroll
    for (int i = 0; i < 16; ++i) {
        int idx = i * 256 + t;
        int d = idx >> 6, sl = idx & 63;
        Vt[(size_t)bh * S * D + (size_t)d * S + s0 + sl] = __float2bfloat16(tile[sl][d]);
    }
}

// Main: block = (bh, 128 q-rows[, key-half]). 4 waves = 4 q-quarters of 32 rows;
// each wave handles BOTH 32-key halves of each 64-key tile (no cross-wave reduce).
// 3-buffer LDS rotation, counted vmcnt(4), one bare s_barrier per tile (T3/T4).
// LDS tiles [64 rows][8 x 16B units], slot(row,u) = u ^ (row&7) ^ (row>>3) ^ ((u&1)<<2)
// (conflict-free b128 reads, both lane phasings); stage pre-applies the inverse on
// the global source address (G21).
template<bool PARTIAL>
__global__ __launch_bounds__(256) void yoso_main(const __hip_bfloat16* __restrict__ Qn,
                                                 const __hip_bfloat16* __restrict__ Kn,
                                                 const __hip_bfloat16* __restrict__ Vt,
                                                 const int* __restrict__ mask,
                                                 const int* __restrict__ hlen_ptr,
                                                 float* __restrict__ outp) {
    __shared__ char lds[3][16384];   // per buf: [0,8192)=K tile, [8192,16384)=V tile

    const int blk = blockIdx.x;
    int bh, q0, khalf;
    if (PARTIAL) { bh = blk >> 5; int r = blk & 31; q0 = (r >> 1) << 7; khalf = r & 1; }
    else         { bh = blk >> 4; q0 = (blk & 15) << 7;                 khalf = 0; }
    const int NTt  = PARTIAL ? 16 : 32;        // 64-key tiles
    const int kbase = khalf << 10;

    const int b    = bh / 12;
    const int t    = threadIdx.x;
    const int w    = t >> 6;
    const int lane = t & 63;
    const int h    = lane >> 5;
    const int c31  = lane & 31;
    const int hcode = hlen_ptr[0];
    const size_t head = (size_t)bh * S * D;

    // ---- staging source offsets (inverse swizzle on global address) ----
    const int s_  = lane & 7;
    const int r3l = lane >> 3;
    const int e1  = s_ ^ r3l ^ w;
    const int u1  = e1 ^ ((e1 & 1) << 2);
    const int u2  = u1 ^ 4;
    const int kgo1 = (8 * w + r3l) * 128 + u1 * 16;
    const int kgo2 = (8 * w + r3l + 32) * 128 + u2 * 16;
    const int vgo1 = (8 * w + r3l) * 4096 + u1 * 16;
    const int vgo2 = (8 * w + r3l + 32) * 4096 + u2 * 16;
    const char* Kg = (const char*)(Kn + head);   // key-row stride 128 B
    const char* Vg = (const char*)(Vt + head);   // d-row stride 4096 B

    // ---- LDS read offsets per key-half (loop-invariant) ----
    char* ldsc = &lds[0][0];
    int koffs[2][4], voffs[2][2][2];
    #pragma unroll
    for (int kh2 = 0; kh2 < 2; ++kh2) {
        int krow = kh2 * 32 + c31;
        int kb3  = (krow & 7) ^ (krow >> 3) ^ (h << 2) ^ h;
        #pragma unroll
        for (int kd = 0; kd < 4; ++kd)
            koffs[kh2][kd] = krow * 128 + (((2 * kd) ^ kb3)) * 16;
        int vb3 = (c31 & 7) ^ (c31 >> 3) ^ (h << 2) ^ h ^ (kh2 << 2);
        #pragma unroll
        for (int kb2 = 0; kb2 < 2; ++kb2) {
            voffs[kh2][kb2][0] = c31 * 128        + (((kb2 << 1) ^ vb3)) * 16     + 8192;
            voffs[kh2][kb2][1] = (32 + c31) * 128 + (((kb2 << 1) ^ vb3 ^ 4)) * 16 + 8192;
        }
    }

    // Q B-fragments: wave w owns q rows q0 + w*32 + c31
    bf16x8 qf[4];
    {
        const __hip_bfloat16* qp = Qn + head + (size_t)(q0 + w * 32 + c31) * D + h * 8;
        qf[0] = *(const bf16x8*)(qp);
        qf[1] = *(const bf16x8*)(qp + 16);
        qf[2] = *(const bf16x8*)(qp + 32);
        qf[3] = *(const bf16x8*)(qp + 48);
    }
    // pin Q loads here so the compiler doesn't emit a vmcnt wait inside the loop
    asm volatile("" :: "v"(qf[0]), "v"(qf[1]), "v"(qf[2]), "v"(qf[3]));

    const f32x16 z16 = {0,0,0,0,0,0,0,0,0,0,0,0,0,0,0,0};
    f32x16 xacc0 = z16, xacc1 = z16;

    const bool  p9 = (hcode == 9);
    const float hf = (float)hcode;
    const f32x2 cq3 = {-0.00596128f, -0.00596128f};
    const f32x2 cq2 = {-0.00575336f, -0.00575336f};
    const f32x2 cq1 = {-0.03812704f, -0.03812704f};
    const f32x2 cq0 = {-0.4501324f,  -0.4501324f};
    const f32x2 chf = {0.5f, 0.5f};

    auto STAGE = [&](int base, int k0) {
        const char* kb = Kg + (size_t)k0 * 128;
        const char* vb = Vg + (size_t)k0 * 2;
        char* Kl = ldsc + base;
        char* Vl = Kl + 8192;
        GLOAD16(kb + kgo1, Kl + w * 1024);
        GLOAD16(kb + kgo2, Kl + (w + 4) * 1024);
        GLOAD16(vb + vgo1, Vl + w * 1024);
        GLOAD16(vb + vgo2, Vl + (w + 4) * 1024);
    };

    auto COMPUTE = [&](int bufbase) {
        const char* base = ldsc + bufbase;
        #pragma unroll
        for (int kh2 = 0; kh2 < 2; ++kh2) {
            // S^T = K_half @ Q^T : C[row=key][col=q]
            __builtin_amdgcn_s_setprio(1);
            f32x16 sacc = __builtin_amdgcn_mfma_f32_32x32x16_bf16(
                *(const bf16x8*)(base + koffs[kh2][0]), qf[0], z16, 0, 0, 0);
            #pragma unroll
            for (int kd = 1; kd < 4; ++kd)
                sacc = __builtin_amdgcn_mfma_f32_32x32x16_bf16(
                    *(const bf16x8*)(base + koffs[kh2][kd]), qf[kd], sacc, 0, 0, 0);
            __builtin_amdgcn_s_setprio(0);

            // w = x^h, x = 0.5 + copysign(0.5 - sqrt(z)*q(z), s), z = 1-|s|
            int u_[8];
            #pragma unroll
            for (int i = 0; i < 8; ++i) {
                f32x2 sv = { sacc[2 * i], sacc[2 * i + 1] };
                f32x2 zz = { fmaxf(1.0f - fabsf(sv.x), 0.0f),
                             fmaxf(1.0f - fabsf(sv.y), 0.0f) };
                f32x2 qq = pk_fma(cq3, zz, cq2);
                qq = pk_fma(qq, zz, cq1);
                qq = pk_fma(qq, zz, cq0);
                f32x2 rt = { __builtin_amdgcn_sqrtf(zz.x), __builtin_amdgcn_sqrtf(zz.y) };
                f32x2 tp = pk_fma(qq, rt, chf);              // 0.5 - q*sqrt(z)
                f32x2 cs = { __builtin_copysignf(tp.x, sv.x),
                             __builtin_copysignf(tp.y, sv.y) };
                f32x2 xs = pk_add(cs, chf);
                f32x2 wv;
                if (p9) {
                    f32x2 x2 = pk_mul(xs, xs);
                    f32x2 x4 = pk_mul(x2, x2);
                    f32x2 x8 = pk_mul(x4, x4);
                    wv = pk_mul(x8, xs);
                } else {
                    wv.x = __builtin_amdgcn_exp2f(hf * __builtin_amdgcn_logf(xs.x));
                    wv.y = __builtin_amdgcn_exp2f(hf * __builtin_amdgcn_logf(xs.y));
                }
                u_[i] = cvtpk_bf16(wv.x, wv.y);
            }
            asm("v_permlane32_swap_b32 %0, %1" : "+v"(u_[0]), "+v"(u_[2]));
            asm("v_permlane32_swap_b32 %0, %1" : "+v"(u_[1]), "+v"(u_[3]));
            asm("v_permlane32_swap_b32 %0, %1" : "+v"(u_[4]), "+v"(u_[6]));
            asm("v_permlane32_swap_b32 %0, %1" : "+v"(u_[5]), "+v"(u_[7]));
            union { int i[4]; bf16x8 v; } f0, f1;
            f0.i[0] = u_[0]; f0.i[1] = u_[1]; f0.i[2] = u_[2]; f0.i[3] = u_[3];
            f1.i[0] = u_[4]; f1.i[1] = u_[5]; f1.i[2] = u_[6]; f1.i[3] = u_[7];

            // X += P_half @ V_half
            bf16x8 vf00 = *(const bf16x8*)(base + voffs[kh2][0][0]);
            bf16x8 vf01 = *(const bf16x8*)(base + voffs[kh2][0][1]);
            bf16x8 vf10 = *(const bf16x8*)(base + voffs[kh2][1][0]);
            bf16x8 vf11 = *(const bf16x8*)(base + voffs[kh2][1][1]);
            __builtin_amdgcn_s_setprio(1);
            xacc0 = __builtin_amdgcn_mfma_f32_32x32x16_bf16(f0.v, vf00, xacc0, 0, 0, 0);
            xacc1 = __builtin_amdgcn_mfma_f32_32x32x16_bf16(f0.v, vf01, xacc1, 0, 0, 0);
            xacc0 = __builtin_amdgcn_mfma_f32_32x32x16_bf16(f1.v, vf10, xacc0, 0, 0, 0);
            xacc1 = __builtin_amdgcn_mfma_f32_32x32x16_bf16(f1.v, vf11, xacc1, 0, 0, 0);
            __builtin_amdgcn_s_setprio(0);
        }
    };

    // ---- main loop: 3-buffer rotation, counted vmcnt, 1 bare barrier/tile ----
    int bA = 0, bB = 16384, bC = 32768;
    STAGE(bA, kbase);
    STAGE(bB, kbase + 64);
    for (int t2 = 0; t2 < NTt; ++t2) {
        if (t2 < NTt - 1) { asm volatile("s_waitcnt vmcnt(4)" ::: "memory"); }
        else              { asm volatile("s_waitcnt vmcnt(0)" ::: "memory"); }
        __builtin_amdgcn_s_barrier();
        if (t2 + 2 < NTt) STAGE(bC, kbase + (t2 + 2) * 64);
        COMPUTE(bA);
        int tmp = bA; bA = bB; bB = bC; bC = tmp;
    }

    // epilogue: per-wave complete 32x64 output
    #pragma unroll
    for (int r = 0; r < 16; ++r) {
        int q  = (r & 3) + 8 * (r >> 2) + 4 * h;
        int qg = q0 + w * 32 + q;
        if (PARTIAL) {
            float* pp = outp + ((size_t)(khalf * NBH + bh) * S + qg) * D;
            pp[c31]      = xacc0[r];
            pp[32 + c31] = xacc1[r];
        } else {
            float mq = (float)mask[b * S + qg];
            float x0 = xacc0[r] * mq, x1 = xacc1[r] * mq;
            float ss = x0 * x0 + x1 * x1;
            #pragma unroll
            for (int m = 1; m <= 16; m <<= 1) ss += __shfl_xor(ss, m, 64);
            float sc = rsqrtf(ss + 1e-6f);
            float* op = outp + ((size_t)bh * S + qg) * D;
            op[c31]      = x0 * sc;
            op[32 + c31] = x1 * sc;
        }
    }
}

// Pass 2 (float4-vectorized): sum key-half partials, query mask, L2-normalize.
__global__ __launch_bounds__(256) void combine_norm(const float* __restrict__ P,
                                                    const int* __restrict__ mask,
                                                    float* __restrict__ out) {
    int t = threadIdx.x;
    int l16 = t & 15;
    size_t row = (size_t)blockIdx.x * 16 + (t >> 4);   // 0..49151
    size_t i = row * 64 + l16 * 4;
    float4 a = *(const float4*)(P + i);
    float4 c = *(const float4*)(P + (size_t)NBH * S * D + i);
    int bh = (int)(row >> 11);
    int sidx = (int)(row & 2047);
    int b = bh / 12;
    float mq = (float)mask[b * S + sidx];
    float x0 = (a.x + c.x) * mq, x1 = (a.y + c.y) * mq;
    float x2 = (a.z + c.z) * mq, x3 = (a.w + c.w) * mq;
    float ss = x0 * x0 + x1 * x1 + x2 * x2 + x3 * x3;
    #pragma unroll
    for (int m = 1; m <= 8; m <<= 1) ss += __shfl_xor(ss, m, 64);
    float sc = rsqrtf(ss + 1e-6f);
    float4 o = { x0 * sc, x1 * sc, x2 * sc, x3 * sc };
    *(float4*)(out + i) = o;
}

extern "C" void kernel_launch(void* const* d_in, const int* in_sizes, int n_in,
                              void* d_out, int out_size, void* d_ws, size_t ws_size,
                              hipStream_t stream) {
    const float* Q    = (const float*)d_in[0];
    const float* K    = (const float*)d_in[1];
    const float* V    = (const float*)d_in[2];
    const int*   mask = (const int*)d_in[3];
    const int*   hlen = (const int*)d_in[4];
    float*       out  = (float*)d_out;

    __hip_bfloat16* Qn = (__hip_bfloat16*)d_ws;
    __hip_bfloat16* Kn = Qn + (size_t)NBH * S * D;
    __hip_bfloat16* Vt = Kn + (size_t)NBH * S * D;
    float* Pbuf = (float*)((char*)d_ws + 3ull * NBH * S * D * 2);  // 2x partials fp32

    const size_t ws_need = 3ull * NBH * S * D * 2 + 2ull * NBH * S * D * 4;

    prep<<<2 * NBH * S / 16 + NBH * 32, 256, 0, stream>>>(Q, K, V, mask, Qn, Kn, Vt);
    if (ws_size >= ws_need) {
        yoso_main<true><<<NBH * 32, 256, 0, stream>>>(Qn, Kn, Vt, mask, hlen, Pbuf);
        combine_norm<<<NBH * S / 16, 256, 0, stream>>>(Pbuf, mask, out);
    } else {
        yoso_main<false><<<NBH * 16, 256, 0, stream>>>(Qn, Kn, Vt, mask, hlen, out);
    }
}

// Round 8
// 81.908 us; speedup vs baseline: 1.4766x; 1.0356x over previous
//
#include <hip/hip_runtime.h>
#include <hip/hip_bf16.h>
#include <hip/hip_fp16.h>

typedef short bf16x8 __attribute__((ext_vector_type(8)));
typedef float f32x16 __attribute__((ext_vector_type(16)));

#define S 2048
#define D 64
#define NBH 24

#define GLOAD16(g, l) __builtin_amdgcn_global_load_lds(                      \
    (const __attribute__((address_space(1))) unsigned int*)(g),              \
    (__attribute__((address_space(3))) unsigned int*)(l), 16, 0, 0)

__device__ __forceinline__ int cvtpk_bf16(float lo, float hi) {
    int r;
    asm("v_cvt_pk_bf16_f32 %0, %1, %2" : "=v"(r) : "v"(lo), "v"(hi));
    return r;
}

// Fused prep (float4-vectorized): L2-normalize Q,K rows (fp32->bf16) + transpose V
// with key-mask fold.
__global__ __launch_bounds__(256) void prep(const float* __restrict__ Q,
                                            const float* __restrict__ K,
                                            const float* __restrict__ V,
                                            const int* __restrict__ mask,
                                            __hip_bfloat16* __restrict__ Qn,
                                            __hip_bfloat16* __restrict__ Kn,
                                            __hip_bfloat16* __restrict__ Vt) {
    __shared__ float tile[64][65];
    const int NBQK = 2 * NBH * S / 16;            // 6144 norm blocks
    int blk = blockIdx.x;
    int t = threadIdx.x;
    if (blk < NBQK) {
        int l16 = t & 15;
        int row = blk * 16 + (t >> 4);
        int half = row >= NBH * S;
        const float* in = half ? K : Q;
        __hip_bfloat16* out = half ? Kn : Qn;
        row -= half * NBH * S;
        float4 x = *(const float4*)(in + (size_t)row * 64 + l16 * 4);
        float ss = x.x * x.x + x.y * x.y + x.z * x.z + x.w * x.w;
        #pragma unroll
        for (int m = 1; m <= 8; m <<= 1) ss += __shfl_xor(ss, m, 64);
        float sc = rsqrtf(ss + 1e-6f);
        int2 pk = { cvtpk_bf16(x.x * sc, x.y * sc), cvtpk_bf16(x.z * sc, x.w * sc) };
        *(int2*)(out + (size_t)row * 64 + l16 * 4) = pk;
        return;
    }
    blk -= NBQK;                                  // 768 transpose blocks
    int bh = blk >> 5;
    int b  = bh / 12;
    int s0 = (blk & 31) << 6;
    #pragma unroll
    for (int i = 0; i < 16; ++i) {
        int idx = i * 256 + t;
        int sl = idx >> 6, d = idx & 63;
        float mv = (float)mask[b * S + s0 + sl];
        tile[sl][d] = V[(size_t)bh * S * D + (size_t)(s0 + sl) * D + d] * mv;
    }
    __syncthreads();
    #pragma unroll
    for (int i = 0; i < 16; ++i) {
        int idx = i * 256 + t;
        int d = idx >> 6, sl = idx & 63;
        Vt[(size_t)bh * S * D + (size_t)d * S + s0 + sl] = __float2bfloat16(tile[sl][d]);
    }
}

// Main: block = (bh, 128 q-rows, key-range S/SPLITS). 4 waves = 4 q-quarters of
// 32 rows; each wave covers both 32-key halves of each 64-key tile.
// 2-buffer 32KB LDS. SOUND schedule (R7 post-mortem): per tile
//   vmcnt(0) [own loads, issued one COMPUTE ago] -> s_barrier [cross-wave
//   publish] -> STAGE(next buf) [WAR-safe: all waves finished computing that
//   buf before this barrier] -> COMPUTE(cur).
// NEVER wait vmcnt AFTER the barrier: vmcnt is per-wave and cannot publish
// other waves' global_load_lds writes.
// LDS slot(row,u) = u ^ (row&7) ^ (row>>3) ^ ((u&1)<<2) (conflict-free b128,
// both lane phasings); stage pre-applies the inverse on the global source (G21).
template<int SPLITS>
__global__ __launch_bounds__(256) void yoso_main(const __hip_bfloat16* __restrict__ Qn,
                                                 const __hip_bfloat16* __restrict__ Kn,
                                                 const __hip_bfloat16* __restrict__ Vt,
                                                 const int* __restrict__ mask,
                                                 const int* __restrict__ hlen_ptr,
                                                 void* __restrict__ outp) {
    __shared__ char lds[2][16384];   // per buf: [0,8192)=K tile, [8192,16384)=V tile

    const int QT = 16;                            // 128-q tiles
    const int blk = blockIdx.x;
    const int bh  = blk / (QT * SPLITS);
    const int rr  = blk % (QT * SPLITS);
    const int q0  = (rr / SPLITS) << 7;
    const int kq  = rr % SPLITS;
    const int kbase = kq * (S / SPLITS);
    const int NTt   = S / SPLITS / 64;

    const int b    = bh / 12;
    const int t    = threadIdx.x;
    const int w    = t >> 6;
    const int lane = t & 63;
    const int h    = lane >> 5;
    const int c31  = lane & 31;
    const int hcode = hlen_ptr[0];
    const size_t head = (size_t)bh * S * D;

    // ---- staging source offsets (inverse swizzle on global address) ----
    const int s_  = lane & 7;
    const int r3l = lane >> 3;
    const int e1  = s_ ^ r3l ^ w;
    const int u1  = e1 ^ ((e1 & 1) << 2);
    const int u2  = u1 ^ 4;
    const int kgo1 = (8 * w + r3l) * 128 + u1 * 16;
    const int kgo2 = (8 * w + r3l + 32) * 128 + u2 * 16;
    const int vgo1 = (8 * w + r3l) * 4096 + u1 * 16;
    const int vgo2 = (8 * w + r3l + 32) * 4096 + u2 * 16;
    const char* Kg = (const char*)(Kn + head);   // key-row stride 128 B
    const char* Vg = (const char*)(Vt + head);   // d-row stride 4096 B

    // ---- LDS read offsets per key-half (loop-invariant) ----
    char* ldsc = &lds[0][0];
    int koffs[2][4], voffs[2][2][2];
    #pragma unroll
    for (int kh2 = 0; kh2 < 2; ++kh2) {
        int krow = kh2 * 32 + c31;
        int kb3  = (krow & 7) ^ (krow >> 3) ^ (h << 2) ^ h;
        #pragma unroll
        for (int kd = 0; kd < 4; ++kd)
            koffs[kh2][kd] = krow * 128 + (((2 * kd) ^ kb3)) * 16;
        int vb3 = (c31 & 7) ^ (c31 >> 3) ^ (h << 2) ^ h ^ (kh2 << 2);
        #pragma unroll
        for (int kb2 = 0; kb2 < 2; ++kb2) {
            voffs[kh2][kb2][0] = c31 * 128        + (((kb2 << 1) ^ vb3)) * 16     + 8192;
            voffs[kh2][kb2][1] = (32 + c31) * 128 + (((kb2 << 1) ^ vb3 ^ 4)) * 16 + 8192;
        }
    }

    // Q B-fragments: wave w owns q rows q0 + w*32 + c31
    bf16x8 qf[4];
    {
        const __hip_bfloat16* qp = Qn + head + (size_t)(q0 + w * 32 + c31) * D + h * 8;
        qf[0] = *(const bf16x8*)(qp);
        qf[1] = *(const bf16x8*)(qp + 16);
        qf[2] = *(const bf16x8*)(qp + 32);
        qf[3] = *(const bf16x8*)(qp + 48);
    }
    asm volatile("" :: "v"(qf[0]), "v"(qf[1]), "v"(qf[2]), "v"(qf[3]));

    const f32x16 z16 = {0,0,0,0,0,0,0,0,0,0,0,0,0,0,0,0};
    f32x16 xacc0 = z16, xacc1 = z16;

    const bool  p9 = (hcode == 9);
    const float hf = (float)hcode;

    auto STAGE = [&](int base, int k0) {
        const char* kb = Kg + (size_t)k0 * 128;
        const char* vb = Vg + (size_t)k0 * 2;
        char* Kl = ldsc + base;
        char* Vl = Kl + 8192;
        GLOAD16(kb + kgo1, Kl + w * 1024);
        GLOAD16(kb + kgo2, Kl + (w + 4) * 1024);
        GLOAD16(vb + vgo1, Vl + w * 1024);
        GLOAD16(vb + vgo2, Vl + (w + 4) * 1024);
    };

    // plain-scalar transform: w = x^h, x = 0.5 + copysign(0.5 - sqrt(z)*q(z), s)
    auto XF = [&](float s) -> float {
        float z  = fmaxf(1.0f - fabsf(s), 0.0f);
        float qp = ((0.00596128f * z + 0.00575336f) * z + 0.03812704f) * z + 0.4501324f;
        float tp = 0.5f - __builtin_amdgcn_sqrtf(z) * qp;   // 0.5 - acos(|s|)/pi >= 0
        float x  = 0.5f + __builtin_copysignf(tp, s);
        if (p9) {
            float x2 = x * x;
            float x4 = x2 * x2;
            return x4 * x4 * x;
        }
        return __builtin_amdgcn_exp2f(hf * __builtin_amdgcn_logf(x));
    };

    auto COMPUTE = [&](int bufbase) {
        const char* base = ldsc + bufbase;
        #pragma unroll
        for (int kh2 = 0; kh2 < 2; ++kh2) {
            // S^T = K_half @ Q^T : C[row=key][col=q]
            __builtin_amdgcn_s_setprio(1);
            f32x16 sacc = __builtin_amdgcn_mfma_f32_32x32x16_bf16(
                *(const bf16x8*)(base + koffs[kh2][0]), qf[0], z16, 0, 0, 0);
            #pragma unroll
            for (int kd = 1; kd < 4; ++kd)
                sacc = __builtin_amdgcn_mfma_f32_32x32x16_bf16(
                    *(const bf16x8*)(base + koffs[kh2][kd]), qf[kd], sacc, 0, 0, 0);
            __builtin_amdgcn_s_setprio(0);

            int u_[8];
            #pragma unroll
            for (int i = 0; i < 8; ++i) {
                float w0 = XF(sacc[2 * i]);
                float w1 = XF(sacc[2 * i + 1]);
                u_[i] = cvtpk_bf16(w0, w1);
            }
            asm("v_permlane32_swap_b32 %0, %1" : "+v"(u_[0]), "+v"(u_[2]));
            asm("v_permlane32_swap_b32 %0, %1" : "+v"(u_[1]), "+v"(u_[3]));
            asm("v_permlane32_swap_b32 %0, %1" : "+v"(u_[4]), "+v"(u_[6]));
            asm("v_permlane32_swap_b32 %0, %1" : "+v"(u_[5]), "+v"(u_[7]));
            union { int i[4]; bf16x8 v; } f0, f1;
            f0.i[0] = u_[0]; f0.i[1] = u_[1]; f0.i[2] = u_[2]; f0.i[3] = u_[3];
            f1.i[0] = u_[4]; f1.i[1] = u_[5]; f1.i[2] = u_[6]; f1.i[3] = u_[7];

            // X += P_half @ V_half
            bf16x8 vf00 = *(const bf16x8*)(base + voffs[kh2][0][0]);
            bf16x8 vf01 = *(const bf16x8*)(base + voffs[kh2][0][1]);
            bf16x8 vf10 = *(const bf16x8*)(base + voffs[kh2][1][0]);
            bf16x8 vf11 = *(const bf16x8*)(base + voffs[kh2][1][1]);
            __builtin_amdgcn_s_setprio(1);
            xacc0 = __builtin_amdgcn_mfma_f32_32x32x16_bf16(f0.v, vf00, xacc0, 0, 0, 0);
            xacc1 = __builtin_amdgcn_mfma_f32_32x32x16_bf16(f0.v, vf01, xacc1, 0, 0, 0);
            xacc0 = __builtin_amdgcn_mfma_f32_32x32x16_bf16(f1.v, vf10, xacc0, 0, 0, 0);
            xacc1 = __builtin_amdgcn_mfma_f32_32x32x16_bf16(f1.v, vf11, xacc1, 0, 0, 0);
            __builtin_amdgcn_s_setprio(0);
        }
    };

    // ---- main loop: drain -> barrier -> stage-next -> compute ----
    STAGE(0, kbase);
    for (int t2 = 0; t2 < NTt; ++t2) {
        asm volatile("s_waitcnt vmcnt(0)" ::: "memory");
        __builtin_amdgcn_s_barrier();
        if (t2 + 1 < NTt) STAGE(((t2 + 1) & 1) * 16384, kbase + (t2 + 1) * 64);
        COMPUTE((t2 & 1) * 16384);
    }

    // epilogue: per-wave complete 32x64 output
    #pragma unroll
    for (int r = 0; r < 16; ++r) {
        int q  = (r & 3) + 8 * (r >> 2) + 4 * h;
        int qg = q0 + w * 32 + q;
        if (SPLITS > 1) {
            __half* pp = (__half*)outp + ((size_t)(kq * NBH + bh) * S + qg) * D;
            pp[c31]      = __float2half(xacc0[r]);
            pp[32 + c31] = __float2half(xacc1[r]);
        } else {
            float mq = (float)mask[b * S + qg];
            float x0 = xacc0[r] * mq, x1 = xacc1[r] * mq;
            float ss = x0 * x0 + x1 * x1;
            #pragma unroll
            for (int m = 1; m <= 16; m <<= 1) ss += __shfl_xor(ss, m, 64);
            float sc = rsqrtf(ss + 1e-6f);
            float* op = (float*)outp + ((size_t)bh * S + qg) * D;
            op[c31]      = x0 * sc;
            op[32 + c31] = x1 * sc;
        }
    }
}

// Pass 2: sum fp16 key-split partials, query mask, L2-normalize, fp32 out.
template<int SPLITS>
__global__ __launch_bounds__(256) void combine_norm(const __half* __restrict__ P,
                                                    const int* __restrict__ mask,
                                                    float* __restrict__ out) {
    int t = threadIdx.x;
    int l16 = t & 15;
    size_t row = (size_t)blockIdx.x * 16 + (t >> 4);
    size_t i = row * 64 + l16 * 4;
    float x0 = 0.f, x1 = 0.f, x2 = 0.f, x3 = 0.f;
    #pragma unroll
    for (int k = 0; k < SPLITS; ++k) {
        const __half2* p2 = (const __half2*)(P + (size_t)k * NBH * S * D + i);
        __half2 ab = p2[0], cd = p2[1];
        x0 += __low2float(ab); x1 += __high2float(ab);
        x2 += __low2float(cd); x3 += __high2float(cd);
    }
    int bh = (int)(row >> 11);
    int sidx = (int)(row & 2047);
    int b = bh / 12;
    float mq = (float)mask[b * S + sidx];
    x0 *= mq; x1 *= mq; x2 *= mq; x3 *= mq;
    float ss = x0 * x0 + x1 * x1 + x2 * x2 + x3 * x3;
    #pragma unroll
    for (int m = 1; m <= 8; m <<= 1) ss += __shfl_xor(ss, m, 64);
    float sc = rsqrtf(ss + 1e-6f);
    float4 o = { x0 * sc, x1 * sc, x2 * sc, x3 * sc };
    *(float4*)(out + i) = o;
}

extern "C" void kernel_launch(void* const* d_in, const int* in_sizes, int n_in,
                              void* d_out, int out_size, void* d_ws, size_t ws_size,
                              hipStream_t stream) {
    const float* Q    = (const float*)d_in[0];
    const float* K    = (const float*)d_in[1];
    const float* V    = (const float*)d_in[2];
    const int*   mask = (const int*)d_in[3];
    const int*   hlen = (const int*)d_in[4];
    float*       out  = (float*)d_out;

    __hip_bfloat16* Qn = (__hip_bfloat16*)d_ws;
    __hip_bfloat16* Kn = Qn + (size_t)NBH * S * D;
    __hip_bfloat16* Vt = Kn + (size_t)NBH * S * D;
    __half* Pbuf = (__half*)((char*)d_ws + 3ull * NBH * S * D * 2);  // fp16 partials

    const size_t base_b = 3ull * NBH * S * D * 2;
    const size_t part_h = (size_t)NBH * S * D * 2;   // one fp16 partial buffer

    prep<<<2 * NBH * S / 16 + NBH * 32, 256, 0, stream>>>(Q, K, V, mask, Qn, Kn, Vt);
    if (ws_size >= base_b + 4 * part_h) {            // 44.04 MB (proven budget)
        yoso_main<4><<<NBH * 16 * 4, 256, 0, stream>>>(Qn, Kn, Vt, mask, hlen, Pbuf);
        combine_norm<4><<<NBH * S / 16, 256, 0, stream>>>(Pbuf, mask, out);
    } else if (ws_size >= base_b + 2 * part_h) {
        yoso_main<2><<<NBH * 16 * 2, 256, 0, stream>>>(Qn, Kn, Vt, mask, hlen, Pbuf);
        combine_norm<2><<<NBH * S / 16, 256, 0, stream>>>(Pbuf, mask, out);
    } else {
        yoso_main<1><<<NBH * 16, 256, 0, stream>>>(Qn, Kn, Vt, mask, hlen, out);
    }
}

// Round 11
// 72.548 us; speedup vs baseline: 1.6671x; 1.1290x over previous
//
#include <hip/hip_runtime.h>
#include <hip/hip_bf16.h>
#include <hip/hip_fp16.h>

typedef short bf16x8 __attribute__((ext_vector_type(8)));
typedef _Float16 h8 __attribute__((ext_vector_type(8)));
typedef _Float16 h2v __attribute__((ext_vector_type(2)));
typedef __fp16 fp16x2 __attribute__((ext_vector_type(2)));   // cvt_pkrtz return type
typedef float f32x16 __attribute__((ext_vector_type(16)));
typedef unsigned int uint32;

#define S 2048
#define D 64
#define NBH 24

#define GLOAD16(g, l) __builtin_amdgcn_global_load_lds(                      \
    (const __attribute__((address_space(1))) unsigned int*)(g),              \
    (__attribute__((address_space(3))) unsigned int*)(l), 16, 0, 0)

__device__ __forceinline__ int cvtpk_bf16(float lo, float hi) {
    int r;
    asm("v_cvt_pk_bf16_f32 %0, %1, %2" : "=v"(r) : "v"(lo), "v"(hi));
    return r;
}

// Fused prep (float4-vectorized): L2-normalize Q,K rows (fp32->bf16) + transpose V
// (fp16, key-mask folded in).
__global__ __launch_bounds__(256) void prep(const float* __restrict__ Q,
                                            const float* __restrict__ K,
                                            const float* __restrict__ V,
                                            const int* __restrict__ mask,
                                            __hip_bfloat16* __restrict__ Qn,
                                            __hip_bfloat16* __restrict__ Kn,
                                            __half* __restrict__ Vt) {
    __shared__ float tile[64][65];
    const int NBQK = 2 * NBH * S / 16;            // 6144 norm blocks
    int blk = blockIdx.x;
    int t = threadIdx.x;
    if (blk < NBQK) {
        int l16 = t & 15;
        int row = blk * 16 + (t >> 4);
        int half = row >= NBH * S;
        const float* in = half ? K : Q;
        __hip_bfloat16* out = half ? Kn : Qn;
        row -= half * NBH * S;
        float4 x = *(const float4*)(in + (size_t)row * 64 + l16 * 4);
        float ss = x.x * x.x + x.y * x.y + x.z * x.z + x.w * x.w;
        #pragma unroll
        for (int m = 1; m <= 8; m <<= 1) ss += __shfl_xor(ss, m, 64);
        float sc = rsqrtf(ss + 1e-6f);
        int2 pk = { cvtpk_bf16(x.x * sc, x.y * sc), cvtpk_bf16(x.z * sc, x.w * sc) };
        *(int2*)(out + (size_t)row * 64 + l16 * 4) = pk;
        return;
    }
    blk -= NBQK;                                  // 768 transpose blocks
    int bh = blk >> 5;
    int b  = bh / 12;
    int s0 = (blk & 31) << 6;
    #pragma unroll
    for (int i = 0; i < 16; ++i) {
        int idx = i * 256 + t;
        int sl = idx >> 6, d = idx & 63;
        float mv = (float)mask[b * S + s0 + sl];
        tile[sl][d] = V[(size_t)bh * S * D + (size_t)(s0 + sl) * D + d] * mv;
    }
    __syncthreads();
    #pragma unroll
    for (int i = 0; i < 16; ++i) {
        int idx = i * 256 + t;
        int d = idx >> 6, sl = idx & 63;
        Vt[(size_t)bh * S * D + (size_t)d * S + s0 + sl] = __float2half(tile[sl][d]);
    }
}

// Main: block = (bh, 128 q-rows, key-range S/SPLITS). 4 waves = 4 q-quarters of
// 32 rows; each wave covers both 32-key halves of each 64-key tile.
// 2-buffer 32KB LDS. SOUND schedule (R7 post-mortem): per tile
//   vmcnt(0) [own loads, issued one COMPUTE ago] -> s_barrier [cross-wave
//   publish] -> STAGE(next buf) [WAR-safe] -> COMPUTE(cur).
// NEVER wait vmcnt AFTER the barrier: vmcnt is per-wave.
// Transform in packed fp16 via native _Float16 vector ops (v_pk_*_f16):
// ~7.5 VALU/elem vs ~13 scalar f32. P and V are fp16; PV uses
// mfma_f32_32x32x16_f16 (fragment layout dtype-independent).
// LDS slot(row,u) = u ^ (row&7) ^ (row>>3) ^ ((u&1)<<2) (conflict-free b128,
// both lane phasings); stage pre-applies the inverse on the global source (G21).
template<int SPLITS>
__global__ __launch_bounds__(256) void yoso_main(const __hip_bfloat16* __restrict__ Qn,
                                                 const __hip_bfloat16* __restrict__ Kn,
                                                 const __half* __restrict__ Vt,
                                                 const int* __restrict__ mask,
                                                 const int* __restrict__ hlen_ptr,
                                                 void* __restrict__ outp) {
    __shared__ char lds[2][16384];   // per buf: [0,8192)=K tile, [8192,16384)=V tile

    const int QT = 16;                            // 128-q tiles
    const int blk = blockIdx.x;
    const int bh  = blk / (QT * SPLITS);
    const int rr  = blk % (QT * SPLITS);
    const int q0  = (rr / SPLITS) << 7;
    const int kq  = rr % SPLITS;
    const int kbase = kq * (S / SPLITS);
    const int NTt   = S / SPLITS / 64;

    const int b    = bh / 12;
    const int t    = threadIdx.x;
    const int w    = t >> 6;
    const int lane = t & 63;
    const int h    = lane >> 5;
    const int c31  = lane & 31;
    const int hcode = hlen_ptr[0];
    const size_t head = (size_t)bh * S * D;

    // ---- staging source offsets (inverse swizzle on global address) ----
    const int s_  = lane & 7;
    const int r3l = lane >> 3;
    const int e1  = s_ ^ r3l ^ w;
    const int u1  = e1 ^ ((e1 & 1) << 2);
    const int u2  = u1 ^ 4;
    const int kgo1 = (8 * w + r3l) * 128 + u1 * 16;
    const int kgo2 = (8 * w + r3l + 32) * 128 + u2 * 16;
    const int vgo1 = (8 * w + r3l) * 4096 + u1 * 16;
    const int vgo2 = (8 * w + r3l + 32) * 4096 + u2 * 16;
    const char* Kg = (const char*)(Kn + head);   // key-row stride 128 B
    const char* Vg = (const char*)(Vt + head);   // d-row stride 4096 B

    // ---- LDS read offsets per key-half (loop-invariant) ----
    char* ldsc = &lds[0][0];
    int koffs[2][4], voffs[2][2][2];
    #pragma unroll
    for (int kh2 = 0; kh2 < 2; ++kh2) {
        int krow = kh2 * 32 + c31;
        int kb3  = (krow & 7) ^ (krow >> 3) ^ (h << 2) ^ h;
        #pragma unroll
        for (int kd = 0; kd < 4; ++kd)
            koffs[kh2][kd] = krow * 128 + (((2 * kd) ^ kb3)) * 16;
        int vb3 = (c31 & 7) ^ (c31 >> 3) ^ (h << 2) ^ h ^ (kh2 << 2);
        #pragma unroll
        for (int kb2 = 0; kb2 < 2; ++kb2) {
            voffs[kh2][kb2][0] = c31 * 128        + (((kb2 << 1) ^ vb3)) * 16     + 8192;
            voffs[kh2][kb2][1] = (32 + c31) * 128 + (((kb2 << 1) ^ vb3 ^ 4)) * 16 + 8192;
        }
    }

    // Q B-fragments: wave w owns q rows q0 + w*32 + c31
    bf16x8 qf[4];
    {
        const __hip_bfloat16* qp = Qn + head + (size_t)(q0 + w * 32 + c31) * D + h * 8;
        qf[0] = *(const bf16x8*)(qp);
        qf[1] = *(const bf16x8*)(qp + 16);
        qf[2] = *(const bf16x8*)(qp + 32);
        qf[3] = *(const bf16x8*)(qp + 48);
    }
    asm volatile("" :: "v"(qf[0]), "v"(qf[1]), "v"(qf[2]), "v"(qf[3]));

    const f32x16 z16 = {0,0,0,0,0,0,0,0,0,0,0,0,0,0,0,0};
    f32x16 xacc0 = z16, xacc1 = z16;

    const bool  p9 = (hcode == 9);
    const float hf = (float)hcode;

    // packed fp16 constants (native vector ops -> v_pk_*_f16)
    const h2v one2  = {(_Float16)1.0f,  (_Float16)1.0f};
    const h2v half2 = {(_Float16)0.5f,  (_Float16)0.5f};
    const h2v zero2 = {(_Float16)0.0f,  (_Float16)0.0f};
    const h2v q3c = {(_Float16)-0.00596128f, (_Float16)-0.00596128f};
    const h2v q2c = {(_Float16)-0.00575336f, (_Float16)-0.00575336f};
    const h2v q1c = {(_Float16)-0.03812704f, (_Float16)-0.03812704f};
    const h2v q0c = {(_Float16)-0.4501324f,  (_Float16)-0.4501324f};

    auto STAGE = [&](int base, int k0) {
        const char* kb = Kg + (size_t)k0 * 128;
        const char* vb = Vg + (size_t)k0 * 2;
        char* Kl = ldsc + base;
        char* Vl = Kl + 8192;
        GLOAD16(kb + kgo1, Kl + w * 1024);
        GLOAD16(kb + kgo2, Kl + (w + 4) * 1024);
        GLOAD16(vb + vgo1, Vl + w * 1024);
        GLOAD16(vb + vgo2, Vl + (w + 4) * 1024);
    };

    // generic-hcode scalar fallback
    auto XFgen = [&](float s) -> float {
        float z  = fmaxf(1.0f - fabsf(s), 0.0f);
        float qp = ((0.00596128f * z + 0.00575336f) * z + 0.03812704f) * z + 0.4501324f;
        float tp = 0.5f - __builtin_amdgcn_sqrtf(z) * qp;
        float x  = 0.5f + __builtin_copysignf(tp, s);
        return __builtin_amdgcn_exp2f(hf * __builtin_amdgcn_logf(x));
    };

    auto COMPUTE = [&](int bufbase) {
        const char* base = ldsc + bufbase;
        #pragma unroll
        for (int kh2 = 0; kh2 < 2; ++kh2) {
            // S^T = K_half @ Q^T : C[row=key][col=q]
            __builtin_amdgcn_s_setprio(1);
            f32x16 sacc = __builtin_amdgcn_mfma_f32_32x32x16_bf16(
                *(const bf16x8*)(base + koffs[kh2][0]), qf[0], z16, 0, 0, 0);
            #pragma unroll
            for (int kd = 1; kd < 4; ++kd)
                sacc = __builtin_amdgcn_mfma_f32_32x32x16_bf16(
                    *(const bf16x8*)(base + koffs[kh2][kd]), qf[kd], sacc, 0, 0, 0);
            __builtin_amdgcn_s_setprio(0);

            // w = x^h, x = 0.5 + copysign(0.5 - sqrt(z)*q(z), s), z = 1-|s|
            // packed fp16: 2 elems per op, sign bits ride along in the pack.
            int u_[8];
            union HU { h2v v; fp16x2 p; uint32 u; };
            if (p9) {
                #pragma unroll
                for (int i = 0; i < 8; ++i) {
                    HU cv; cv.p = __builtin_amdgcn_cvt_pkrtz(sacc[2 * i], sacc[2 * i + 1]);
                    uint32 spb = cv.u;
                    HU za; za.u = spb & 0x7FFF7FFFu;                 // |s|
                    h2v z = one2 - za.v;
                    z = __builtin_elementwise_max(z, zero2);          // max(1-|s|,0)
                    h2v rt = __builtin_elementwise_sqrt(z);
                    h2v q = q3c * z + q2c;                            // -q(z) Horner
                    q = q * z + q1c;
                    q = q * z + q0c;
                    HU tb; tb.v = q * rt + half2;                     // 0.5 - q(z)*sqrt(z) >= 0
                    HU xb; xb.u = (tb.u & 0x7FFF7FFFu) | (spb & 0x80008000u);
                    h2v x = xb.v + half2;                             // 0.5 + copysign(tp, s)
                    h2v x2 = x * x;
                    h2v x4 = x2 * x2;
                    h2v x8 = x4 * x4;
                    HU wr; wr.v = x8 * x;                             // x^9, packed fp16
                    u_[i] = (int)wr.u;
                }
            } else {
                #pragma unroll
                for (int i = 0; i < 8; ++i) {
                    HU cv;
                    cv.p = __builtin_amdgcn_cvt_pkrtz(XFgen(sacc[2 * i]),
                                                      XFgen(sacc[2 * i + 1]));
                    u_[i] = (int)cv.u;
                }
            }
            asm("v_permlane32_swap_b32 %0, %1" : "+v"(u_[0]), "+v"(u_[2]));
            asm("v_permlane32_swap_b32 %0, %1" : "+v"(u_[1]), "+v"(u_[3]));
            asm("v_permlane32_swap_b32 %0, %1" : "+v"(u_[4]), "+v"(u_[6]));
            asm("v_permlane32_swap_b32 %0, %1" : "+v"(u_[5]), "+v"(u_[7]));
            union { int i[4]; h8 v; } f0, f1;
            f0.i[0] = u_[0]; f0.i[1] = u_[1]; f0.i[2] = u_[2]; f0.i[3] = u_[3];
            f1.i[0] = u_[4]; f1.i[1] = u_[5]; f1.i[2] = u_[6]; f1.i[3] = u_[7];

            // X += P_half @ V_half (fp16 MFMA; fragment layout dtype-independent)
            h8 vf00 = *(const h8*)(base + voffs[kh2][0][0]);
            h8 vf01 = *(const h8*)(base + voffs[kh2][0][1]);
            h8 vf10 = *(const h8*)(base + voffs[kh2][1][0]);
            h8 vf11 = *(const h8*)(base + voffs[kh2][1][1]);
            __builtin_amdgcn_s_setprio(1);
            xacc0 = __builtin_amdgcn_mfma_f32_32x32x16_f16(f0.v, vf00, xacc0, 0, 0, 0);
            xacc1 = __builtin_amdgcn_mfma_f32_32x32x16_f16(f0.v, vf01, xacc1, 0, 0, 0);
            xacc0 = __builtin_amdgcn_mfma_f32_32x32x16_f16(f1.v, vf10, xacc0, 0, 0, 0);
            xacc1 = __builtin_amdgcn_mfma_f32_32x32x16_f16(f1.v, vf11, xacc1, 0, 0, 0);
            __builtin_amdgcn_s_setprio(0);
        }
    };

    // ---- main loop: drain -> barrier -> stage-next -> compute ----
    STAGE(0, kbase);
    for (int t2 = 0; t2 < NTt; ++t2) {
        asm volatile("s_waitcnt vmcnt(0)" ::: "memory");
        __builtin_amdgcn_s_barrier();
        if (t2 + 1 < NTt) STAGE(((t2 + 1) & 1) * 16384, kbase + (t2 + 1) * 64);
        COMPUTE((t2 & 1) * 16384);
    }

    // epilogue: per-wave complete 32x64 output
    #pragma unroll
    for (int r = 0; r < 16; ++r) {
        int q  = (r & 3) + 8 * (r >> 2) + 4 * h;
        int qg = q0 + w * 32 + q;
        if (SPLITS > 1) {
            __half* pp = (__half*)outp + ((size_t)(kq * NBH + bh) * S + qg) * D;
            pp[c31]      = __float2half(xacc0[r]);
            pp[32 + c31] = __float2half(xacc1[r]);
        } else {
            float mq = (float)mask[b * S + qg];
            float x0 = xacc0[r] * mq, x1 = xacc1[r] * mq;
            float ss = x0 * x0 + x1 * x1;
            #pragma unroll
            for (int m = 1; m <= 16; m <<= 1) ss += __shfl_xor(ss, m, 64);
            float sc = rsqrtf(ss + 1e-6f);
            float* op = (float*)outp + ((size_t)bh * S + qg) * D;
            op[c31]      = x0 * sc;
            op[32 + c31] = x1 * sc;
        }
    }
}

// Pass 2: sum fp16 key-split partials, query mask, L2-normalize, fp32 out.
template<int SPLITS>
__global__ __launch_bounds__(256) void combine_norm(const __half* __restrict__ P,
                                                    const int* __restrict__ mask,
                                                    float* __restrict__ out) {
    int t = threadIdx.x;
    int l16 = t & 15;
    size_t row = (size_t)blockIdx.x * 16 + (t >> 4);
    size_t i = row * 64 + l16 * 4;
    float x0 = 0.f, x1 = 0.f, x2 = 0.f, x3 = 0.f;
    #pragma unroll
    for (int k = 0; k < SPLITS; ++k) {
        const __half2* p2 = (const __half2*)(P + (size_t)k * NBH * S * D + i);
        __half2 ab = p2[0], cd = p2[1];
        x0 += __low2float(ab); x1 += __high2float(ab);
        x2 += __low2float(cd); x3 += __high2float(cd);
    }
    int bh = (int)(row >> 11);
    int sidx = (int)(row & 2047);
    int b = bh / 12;
    float mq = (float)mask[b * S + sidx];
    x0 *= mq; x1 *= mq; x2 *= mq; x3 *= mq;
    float ss = x0 * x0 + x1 * x1 + x2 * x2 + x3 * x3;
    #pragma unroll
    for (int m = 1; m <= 8; m <<= 1) ss += __shfl_xor(ss, m, 64);
    float sc = rsqrtf(ss + 1e-6f);
    float4 o = { x0 * sc, x1 * sc, x2 * sc, x3 * sc };
    *(float4*)(out + i) = o;
}

extern "C" void kernel_launch(void* const* d_in, const int* in_sizes, int n_in,
                              void* d_out, int out_size, void* d_ws, size_t ws_size,
                              hipStream_t stream) {
    const float* Q    = (const float*)d_in[0];
    const float* K    = (const float*)d_in[1];
    const float* V    = (const float*)d_in[2];
    const int*   mask = (const int*)d_in[3];
    const int*   hlen = (const int*)d_in[4];
    float*       out  = (float*)d_out;

    __hip_bfloat16* Qn = (__hip_bfloat16*)d_ws;
    __hip_bfloat16* Kn = Qn + (size_t)NBH * S * D;
    __half*         Vt = (__half*)(Kn + (size_t)NBH * S * D);
    __half* Pbuf = (__half*)((char*)d_ws + 3ull * NBH * S * D * 2);  // fp16 partials

    const size_t base_b = 3ull * NBH * S * D * 2;
    const size_t part_h = (size_t)NBH * S * D * 2;   // one fp16 partial buffer

    prep<<<2 * NBH * S / 16 + NBH * 32, 256, 0, stream>>>(Q, K, V, mask, Qn, Kn, Vt);
    if (ws_size >= base_b + 4 * part_h) {            // 44.04 MB (proven budget)
        yoso_main<4><<<NBH * 16 * 4, 256, 0, stream>>>(Qn, Kn, Vt, mask, hlen, Pbuf);
        combine_norm<4><<<NBH * S / 16, 256, 0, stream>>>(Pbuf, mask, out);
    } else if (ws_size >= base_b + 2 * part_h) {
        yoso_main<2><<<NBH * 16 * 2, 256, 0, stream>>>(Qn, Kn, Vt, mask, hlen, Pbuf);
        combine_norm<2><<<NBH * S / 16, 256, 0, stream>>>(Pbuf, mask, out);
    } else {
        yoso_main<1><<<NBH * 16, 256, 0, stream>>>(Qn, Kn, Vt, mask, hlen, out);
    }
}

// Round 12
// 67.931 us; speedup vs baseline: 1.7804x; 1.0680x over previous
//
#include <hip/hip_runtime.h>
#include <hip/hip_bf16.h>
#include <hip/hip_fp16.h>

typedef short bf16x8 __attribute__((ext_vector_type(8)));
typedef _Float16 h8 __attribute__((ext_vector_type(8)));
typedef _Float16 h2v __attribute__((ext_vector_type(2)));
typedef __fp16 fp16x2 __attribute__((ext_vector_type(2)));   // cvt_pkrtz return type
typedef float f32x16 __attribute__((ext_vector_type(16)));
typedef unsigned int uint32;

#define S 2048
#define D 64
#define NBH 24

#define GLOAD16(g, l) __builtin_amdgcn_global_load_lds(                      \
    (const __attribute__((address_space(1))) unsigned int*)(g),              \
    (__attribute__((address_space(3))) unsigned int*)(l), 16, 0, 0)

__device__ __forceinline__ int cvtpk_bf16(float lo, float hi) {
    int r;
    asm("v_cvt_pk_bf16_f32 %0, %1, %2" : "=v"(r) : "v"(lo), "v"(hi));
    return r;
}

// Fused prep (float4-vectorized): L2-normalize Q,K rows (fp32->bf16) + transpose V
// (fp16, key-mask folded in).
__global__ __launch_bounds__(256) void prep(const float* __restrict__ Q,
                                            const float* __restrict__ K,
                                            const float* __restrict__ V,
                                            const int* __restrict__ mask,
                                            __hip_bfloat16* __restrict__ Qn,
                                            __hip_bfloat16* __restrict__ Kn,
                                            __half* __restrict__ Vt) {
    __shared__ float tile[64][65];
    const int NBQK = 2 * NBH * S / 16;            // 6144 norm blocks
    int blk = blockIdx.x;
    int t = threadIdx.x;
    if (blk < NBQK) {
        int l16 = t & 15;
        int row = blk * 16 + (t >> 4);
        int half = row >= NBH * S;
        const float* in = half ? K : Q;
        __hip_bfloat16* out = half ? Kn : Qn;
        row -= half * NBH * S;
        float4 x = *(const float4*)(in + (size_t)row * 64 + l16 * 4);
        float ss = x.x * x.x + x.y * x.y + x.z * x.z + x.w * x.w;
        #pragma unroll
        for (int m = 1; m <= 8; m <<= 1) ss += __shfl_xor(ss, m, 64);
        float sc = rsqrtf(ss + 1e-6f);
        int2 pk = { cvtpk_bf16(x.x * sc, x.y * sc), cvtpk_bf16(x.z * sc, x.w * sc) };
        *(int2*)(out + (size_t)row * 64 + l16 * 4) = pk;
        return;
    }
    blk -= NBQK;                                  // 768 transpose blocks
    int bh = blk >> 5;
    int b  = bh / 12;
    int s0 = (blk & 31) << 6;
    #pragma unroll
    for (int i = 0; i < 16; ++i) {
        int idx = i * 256 + t;
        int sl = idx >> 6, d = idx & 63;
        float mv = (float)mask[b * S + s0 + sl];
        tile[sl][d] = V[(size_t)bh * S * D + (size_t)(s0 + sl) * D + d] * mv;
    }
    __syncthreads();
    #pragma unroll
    for (int i = 0; i < 16; ++i) {
        int idx = i * 256 + t;
        int d = idx >> 6, sl = idx & 63;
        Vt[(size_t)bh * S * D + (size_t)d * S + s0 + sl] = __float2half(tile[sl][d]);
    }
}

// Main: 512-thread blocks (8 waves), block = (bh, 256 q-rows, key-range S/SPLITS).
// Grid = 24 x 8 x SPLITS; at SPLITS=4 -> 768 blocks = exactly 3/CU (full residency,
// minimal dispatch tail -- R11 post-mortem: packing, not VALU, binds).
// Each wave owns 32 q-rows and covers both 32-key halves of each 64-key tile.
// 2-buffer 32KB LDS shared by 8 waves. SOUND schedule (R7 post-mortem): per tile
//   vmcnt(0) [own loads, issued one COMPUTE ago] -> s_barrier [cross-wave
//   publish] -> STAGE(next buf) [WAR-safe] -> COMPUTE(cur).
// NEVER wait vmcnt AFTER the barrier: vmcnt is per-wave.
// Transform in packed fp16 via native _Float16 vector ops (v_pk_*_f16); P and V
// fp16, PV uses mfma_f32_32x32x16_f16 (fragment layout dtype-independent).
// LDS slot(row,u) = u ^ (row&7) ^ (row>>3) ^ ((u&1)<<2) (conflict-free b128,
// both lane phasings); stage pre-applies the inverse on the global source (G21).
template<int SPLITS>
__global__ __launch_bounds__(512) void yoso_main(const __hip_bfloat16* __restrict__ Qn,
                                                 const __hip_bfloat16* __restrict__ Kn,
                                                 const __half* __restrict__ Vt,
                                                 const int* __restrict__ mask,
                                                 const int* __restrict__ hlen_ptr,
                                                 void* __restrict__ outp) {
    __shared__ char lds[2][16384];   // per buf: [0,8192)=K tile, [8192,16384)=V tile

    const int QT = 8;                             // 256-q tiles
    const int blk = blockIdx.x;
    const int bh  = blk / (QT * SPLITS);
    const int rr  = blk % (QT * SPLITS);
    const int q0  = (rr / SPLITS) << 8;
    const int kq  = rr % SPLITS;
    const int kbase = kq * (S / SPLITS);
    const int NTt   = S / SPLITS / 64;

    const int b    = bh / 12;
    const int t    = threadIdx.x;
    const int w    = t >> 6;                      // 0..7
    const int lane = t & 63;
    const int h    = lane >> 5;
    const int c31  = lane & 31;
    const int hcode = hlen_ptr[0];
    const size_t head = (size_t)bh * S * D;

    // ---- staging source offsets (inverse swizzle on global address) ----
    // thread t covers LDS row = 8*w + (lane>>3), 16B slot = lane&7 (linear dest).
    const int s_  = lane & 7;
    const int r3l = lane >> 3;
    const int e1  = s_ ^ r3l ^ (w & 7);
    const int u1  = e1 ^ ((e1 & 1) << 2);
    const int kgo1 = (8 * w + r3l) * 128 + u1 * 16;
    const int vgo1 = (8 * w + r3l) * 4096 + u1 * 16;
    const char* Kg = (const char*)(Kn + head);   // key-row stride 128 B
    const char* Vg = (const char*)(Vt + head);   // d-row stride 4096 B

    // ---- LDS read offsets per key-half (loop-invariant, wave-independent) ----
    char* ldsc = &lds[0][0];
    int koffs[2][4], voffs[2][2][2];
    #pragma unroll
    for (int kh2 = 0; kh2 < 2; ++kh2) {
        int krow = kh2 * 32 + c31;
        int kb3  = (krow & 7) ^ (krow >> 3) ^ (h << 2) ^ h;
        #pragma unroll
        for (int kd = 0; kd < 4; ++kd)
            koffs[kh2][kd] = krow * 128 + (((2 * kd) ^ kb3)) * 16;
        int vb3 = (c31 & 7) ^ (c31 >> 3) ^ (h << 2) ^ h ^ (kh2 << 2);
        #pragma unroll
        for (int kb2 = 0; kb2 < 2; ++kb2) {
            voffs[kh2][kb2][0] = c31 * 128        + (((kb2 << 1) ^ vb3)) * 16     + 8192;
            voffs[kh2][kb2][1] = (32 + c31) * 128 + (((kb2 << 1) ^ vb3 ^ 4)) * 16 + 8192;
        }
    }

    // Q B-fragments: wave w owns q rows q0 + w*32 + c31
    bf16x8 qf[4];
    {
        const __hip_bfloat16* qp = Qn + head + (size_t)(q0 + w * 32 + c31) * D + h * 8;
        qf[0] = *(const bf16x8*)(qp);
        qf[1] = *(const bf16x8*)(qp + 16);
        qf[2] = *(const bf16x8*)(qp + 32);
        qf[3] = *(const bf16x8*)(qp + 48);
    }
    asm volatile("" :: "v"(qf[0]), "v"(qf[1]), "v"(qf[2]), "v"(qf[3]));

    const f32x16 z16 = {0,0,0,0,0,0,0,0,0,0,0,0,0,0,0,0};
    f32x16 xacc0 = z16, xacc1 = z16;

    const bool  p9 = (hcode == 9);
    const float hf = (float)hcode;

    // packed fp16 constants (native vector ops -> v_pk_*_f16)
    const h2v one2  = {(_Float16)1.0f,  (_Float16)1.0f};
    const h2v half2 = {(_Float16)0.5f,  (_Float16)0.5f};
    const h2v zero2 = {(_Float16)0.0f,  (_Float16)0.0f};
    const h2v q3c = {(_Float16)-0.00596128f, (_Float16)-0.00596128f};
    const h2v q2c = {(_Float16)-0.00575336f, (_Float16)-0.00575336f};
    const h2v q1c = {(_Float16)-0.03812704f, (_Float16)-0.03812704f};
    const h2v q0c = {(_Float16)-0.4501324f,  (_Float16)-0.4501324f};

    auto STAGE = [&](int base, int k0) {
        const char* kb = Kg + (size_t)k0 * 128;
        const char* vb = Vg + (size_t)k0 * 2;
        char* Kl = ldsc + base;
        char* Vl = Kl + 8192;
        GLOAD16(kb + kgo1, Kl + w * 1024);        // 512 thr x 16B = full 8KB K tile
        GLOAD16(vb + vgo1, Vl + w * 1024);        // full 8KB V tile
    };

    // generic-hcode scalar fallback
    auto XFgen = [&](float s) -> float {
        float z  = fmaxf(1.0f - fabsf(s), 0.0f);
        float qp = ((0.00596128f * z + 0.00575336f) * z + 0.03812704f) * z + 0.4501324f;
        float tp = 0.5f - __builtin_amdgcn_sqrtf(z) * qp;
        float x  = 0.5f + __builtin_copysignf(tp, s);
        return __builtin_amdgcn_exp2f(hf * __builtin_amdgcn_logf(x));
    };

    auto COMPUTE = [&](int bufbase) {
        const char* base = ldsc + bufbase;
        #pragma unroll
        for (int kh2 = 0; kh2 < 2; ++kh2) {
            // S^T = K_half @ Q^T : C[row=key][col=q]
            __builtin_amdgcn_s_setprio(1);
            f32x16 sacc = __builtin_amdgcn_mfma_f32_32x32x16_bf16(
                *(const bf16x8*)(base + koffs[kh2][0]), qf[0], z16, 0, 0, 0);
            #pragma unroll
            for (int kd = 1; kd < 4; ++kd)
                sacc = __builtin_amdgcn_mfma_f32_32x32x16_bf16(
                    *(const bf16x8*)(base + koffs[kh2][kd]), qf[kd], sacc, 0, 0, 0);
            __builtin_amdgcn_s_setprio(0);

            // w = x^h, x = 0.5 + copysign(0.5 - sqrt(z)*q(z), s), z = 1-|s|
            // packed fp16: 2 elems per op, sign bits ride along in the pack.
            int u_[8];
            union HU { h2v v; fp16x2 p; uint32 u; };
            if (p9) {
                #pragma unroll
                for (int i = 0; i < 8; ++i) {
                    HU cv; cv.p = __builtin_amdgcn_cvt_pkrtz(sacc[2 * i], sacc[2 * i + 1]);
                    uint32 spb = cv.u;
                    HU za; za.u = spb & 0x7FFF7FFFu;                 // |s|
                    h2v z = one2 - za.v;
                    z = __builtin_elementwise_max(z, zero2);          // max(1-|s|,0)
                    h2v rt = __builtin_elementwise_sqrt(z);
                    h2v q = q3c * z + q2c;                            // -q(z) Horner
                    q = q * z + q1c;
                    q = q * z + q0c;
                    HU tb; tb.v = q * rt + half2;                     // 0.5 - q(z)*sqrt(z) >= 0
                    HU xb; xb.u = (tb.u & 0x7FFF7FFFu) | (spb & 0x80008000u);
                    h2v x = xb.v + half2;                             // 0.5 + copysign(tp, s)
                    h2v x2 = x * x;
                    h2v x4 = x2 * x2;
                    h2v x8 = x4 * x4;
                    HU wr; wr.v = x8 * x;                             // x^9, packed fp16
                    u_[i] = (int)wr.u;
                }
            } else {
                #pragma unroll
                for (int i = 0; i < 8; ++i) {
                    HU cv;
                    cv.p = __builtin_amdgcn_cvt_pkrtz(XFgen(sacc[2 * i]),
                                                      XFgen(sacc[2 * i + 1]));
                    u_[i] = (int)cv.u;
                }
            }
            asm("v_permlane32_swap_b32 %0, %1" : "+v"(u_[0]), "+v"(u_[2]));
            asm("v_permlane32_swap_b32 %0, %1" : "+v"(u_[1]), "+v"(u_[3]));
            asm("v_permlane32_swap_b32 %0, %1" : "+v"(u_[4]), "+v"(u_[6]));
            asm("v_permlane32_swap_b32 %0, %1" : "+v"(u_[5]), "+v"(u_[7]));
            union { int i[4]; h8 v; } f0, f1;
            f0.i[0] = u_[0]; f0.i[1] = u_[1]; f0.i[2] = u_[2]; f0.i[3] = u_[3];
            f1.i[0] = u_[4]; f1.i[1] = u_[5]; f1.i[2] = u_[6]; f1.i[3] = u_[7];

            // X += P_half @ V_half (fp16 MFMA; fragment layout dtype-independent)
            h8 vf00 = *(const h8*)(base + voffs[kh2][0][0]);
            h8 vf01 = *(const h8*)(base + voffs[kh2][0][1]);
            h8 vf10 = *(const h8*)(base + voffs[kh2][1][0]);
            h8 vf11 = *(const h8*)(base + voffs[kh2][1][1]);
            __builtin_amdgcn_s_setprio(1);
            xacc0 = __builtin_amdgcn_mfma_f32_32x32x16_f16(f0.v, vf00, xacc0, 0, 0, 0);
            xacc1 = __builtin_amdgcn_mfma_f32_32x32x16_f16(f0.v, vf01, xacc1, 0, 0, 0);
            xacc0 = __builtin_amdgcn_mfma_f32_32x32x16_f16(f1.v, vf10, xacc0, 0, 0, 0);
            xacc1 = __builtin_amdgcn_mfma_f32_32x32x16_f16(f1.v, vf11, xacc1, 0, 0, 0);
            __builtin_amdgcn_s_setprio(0);
        }
    };

    // ---- main loop: drain -> barrier -> stage-next -> compute ----
    STAGE(0, kbase);
    for (int t2 = 0; t2 < NTt; ++t2) {
        asm volatile("s_waitcnt vmcnt(0)" ::: "memory");
        __builtin_amdgcn_s_barrier();
        if (t2 + 1 < NTt) STAGE(((t2 + 1) & 1) * 16384, kbase + (t2 + 1) * 64);
        COMPUTE((t2 & 1) * 16384);
    }

    // epilogue: per-wave complete 32x64 output
    #pragma unroll
    for (int r = 0; r < 16; ++r) {
        int q  = (r & 3) + 8 * (r >> 2) + 4 * h;
        int qg = q0 + w * 32 + q;
        if (SPLITS > 1) {
            __half* pp = (__half*)outp + ((size_t)(kq * NBH + bh) * S + qg) * D;
            pp[c31]      = __float2half(xacc0[r]);
            pp[32 + c31] = __float2half(xacc1[r]);
        } else {
            float mq = (float)mask[b * S + qg];
            float x0 = xacc0[r] * mq, x1 = xacc1[r] * mq;
            float ss = x0 * x0 + x1 * x1;
            #pragma unroll
            for (int m = 1; m <= 16; m <<= 1) ss += __shfl_xor(ss, m, 64);
            float sc = rsqrtf(ss + 1e-6f);
            float* op = (float*)outp + ((size_t)bh * S + qg) * D;
            op[c31]      = x0 * sc;
            op[32 + c31] = x1 * sc;
        }
    }
}

// Pass 2: sum fp16 key-split partials, query mask, L2-normalize, fp32 out.
template<int SPLITS>
__global__ __launch_bounds__(256) void combine_norm(const __half* __restrict__ P,
                                                    const int* __restrict__ mask,
                                                    float* __restrict__ out) {
    int t = threadIdx.x;
    int l16 = t & 15;
    size_t row = (size_t)blockIdx.x * 16 + (t >> 4);
    size_t i = row * 64 + l16 * 4;
    float x0 = 0.f, x1 = 0.f, x2 = 0.f, x3 = 0.f;
    #pragma unroll
    for (int k = 0; k < SPLITS; ++k) {
        const __half2* p2 = (const __half2*)(P + (size_t)k * NBH * S * D + i);
        __half2 ab = p2[0], cd = p2[1];
        x0 += __low2float(ab); x1 += __high2float(ab);
        x2 += __low2float(cd); x3 += __high2float(cd);
    }
    int bh = (int)(row >> 11);
    int sidx = (int)(row & 2047);
    int b = bh / 12;
    float mq = (float)mask[b * S + sidx];
    x0 *= mq; x1 *= mq; x2 *= mq; x3 *= mq;
    float ss = x0 * x0 + x1 * x1 + x2 * x2 + x3 * x3;
    #pragma unroll
    for (int m = 1; m <= 8; m <<= 1) ss += __shfl_xor(ss, m, 64);
    float sc = rsqrtf(ss + 1e-6f);
    float4 o = { x0 * sc, x1 * sc, x2 * sc, x3 * sc };
    *(float4*)(out + i) = o;
}

extern "C" void kernel_launch(void* const* d_in, const int* in_sizes, int n_in,
                              void* d_out, int out_size, void* d_ws, size_t ws_size,
                              hipStream_t stream) {
    const float* Q    = (const float*)d_in[0];
    const float* K    = (const float*)d_in[1];
    const float* V    = (const float*)d_in[2];
    const int*   mask = (const int*)d_in[3];
    const int*   hlen = (const int*)d_in[4];
    float*       out  = (float*)d_out;

    __hip_bfloat16* Qn = (__hip_bfloat16*)d_ws;
    __hip_bfloat16* Kn = Qn + (size_t)NBH * S * D;
    __half*         Vt = (__half*)(Kn + (size_t)NBH * S * D);
    __half* Pbuf = (__half*)((char*)d_ws + 3ull * NBH * S * D * 2);  // fp16 partials

    const size_t base_b = 3ull * NBH * S * D * 2;
    const size_t part_h = (size_t)NBH * S * D * 2;   // one fp16 partial buffer

    prep<<<2 * NBH * S / 16 + NBH * 32, 256, 0, stream>>>(Q, K, V, mask, Qn, Kn, Vt);
    if (ws_size >= base_b + 4 * part_h) {            // 44.04 MB (proven budget)
        yoso_main<4><<<NBH * 8 * 4, 512, 0, stream>>>(Qn, Kn, Vt, mask, hlen, Pbuf);
        combine_norm<4><<<NBH * S / 16, 256, 0, stream>>>(Pbuf, mask, out);
    } else if (ws_size >= base_b + 2 * part_h) {
        yoso_main<2><<<NBH * 8 * 2, 512, 0, stream>>>(Qn, Kn, Vt, mask, hlen, Pbuf);
        combine_norm<2><<<NBH * S / 16, 256, 0, stream>>>(Pbuf, mask, out);
    } else {
        yoso_main<1><<<NBH * 8, 512, 0, stream>>>(Qn, Kn, Vt, mask, hlen, out);
    }
}

// Round 14
// 67.814 us; speedup vs baseline: 1.7835x; 1.0017x over previous
//
#include <hip/hip_runtime.h>
#include <hip/hip_bf16.h>
#include <hip/hip_fp16.h>

typedef short bf16x8 __attribute__((ext_vector_type(8)));
typedef _Float16 h8 __attribute__((ext_vector_type(8)));
typedef _Float16 h2v __attribute__((ext_vector_type(2)));
typedef __fp16 fp16x2 __attribute__((ext_vector_type(2)));   // cvt_pkrtz return type
typedef float f32x16 __attribute__((ext_vector_type(16)));
typedef unsigned int uint32;

#define S 2048
#define D 64
#define NBH 24

#define GLOAD16(g, l) __builtin_amdgcn_global_load_lds(                      \
    (const __attribute__((address_space(1))) unsigned int*)(g),              \
    (__attribute__((address_space(3))) unsigned int*)(l), 16, 0, 0)

__device__ __forceinline__ int cvtpk_bf16(float lo, float hi) {
    int r;
    asm("v_cvt_pk_bf16_f32 %0, %1, %2" : "=v"(r) : "v"(lo), "v"(hi));
    return r;
}

// Prep (float4-vectorized): L2-normalize K rows (fp32->bf16) + transpose V
// (fp16, key-mask folded in). Q-normalization is fused into yoso_main.
__global__ __launch_bounds__(256) void prep(const float* __restrict__ K,
                                            const float* __restrict__ V,
                                            const int* __restrict__ mask,
                                            __hip_bfloat16* __restrict__ Kn,
                                            __half* __restrict__ Vt) {
    __shared__ float tile[64][65];
    const int NBK = NBH * S / 16;                 // 3072 K-norm blocks
    int blk = blockIdx.x;
    int t = threadIdx.x;
    if (blk < NBK) {
        int l16 = t & 15;
        int row = blk * 16 + (t >> 4);
        float4 x = *(const float4*)(K + (size_t)row * 64 + l16 * 4);
        float ss = x.x * x.x + x.y * x.y + x.z * x.z + x.w * x.w;
        #pragma unroll
        for (int m = 1; m <= 8; m <<= 1) ss += __shfl_xor(ss, m, 64);
        float sc = rsqrtf(ss + 1e-6f);
        int2 pk = { cvtpk_bf16(x.x * sc, x.y * sc), cvtpk_bf16(x.z * sc, x.w * sc) };
        *(int2*)(Kn + (size_t)row * 64 + l16 * 4) = pk;
        return;
    }
    blk -= NBK;                                   // 768 transpose blocks
    int bh = blk >> 5;
    int b  = bh / 12;
    int s0 = (blk & 31) << 6;
    #pragma unroll
    for (int i = 0; i < 16; ++i) {
        int idx = i * 256 + t;
        int sl = idx >> 6, d = idx & 63;
        float mv = (float)mask[b * S + s0 + sl];
        tile[sl][d] = V[(size_t)bh * S * D + (size_t)(s0 + sl) * D + d] * mv;
    }
    __syncthreads();
    #pragma unroll
    for (int i = 0; i < 16; ++i) {
        int idx = i * 256 + t;
        int d = idx >> 6, sl = idx & 63;
        Vt[(size_t)bh * S * D + (size_t)d * S + s0 + sl] = __float2half(tile[sl][d]);
    }
}

// Main: 512-thread blocks (8 waves), block = (bh, 256 q-rows, key-range S/SPLITS).
// Grid = 24 x 8 x SPLITS; at SPLITS=4 -> 768 blocks = exactly 3/CU.
// Q is normalized IN-KERNEL (fp32 load + row sumsq via shfl_xor(32) + cvt to bf16).
// Each wave owns 32 q-rows and covers both 32-key halves of each 64-key tile.
// 2-buffer 32KB LDS shared by 8 waves. SOUND schedule (R7 post-mortem): per tile
//   vmcnt(0) [own loads, issued one COMPUTE ago] -> s_barrier [cross-wave
//   publish] -> STAGE(next buf) [WAR-safe] -> COMPUTE(cur).
// NEVER wait vmcnt AFTER the barrier: vmcnt is per-wave.
// Transform in packed fp16 via native _Float16 vector ops (v_pk_*_f16); P and V
// fp16, PV uses mfma_f32_32x32x16_f16 (fragment layout dtype-independent).
// LDS slot(row,u) = u ^ (row&7) ^ (row>>3) ^ ((u&1)<<2) (conflict-free b128,
// both lane phasings); stage pre-applies the inverse on the global source (G21).
template<int SPLITS>
__global__ __launch_bounds__(512) void yoso_main(const float* __restrict__ Qf,
                                                 const __hip_bfloat16* __restrict__ Kn,
                                                 const __half* __restrict__ Vt,
                                                 const int* __restrict__ mask,
                                                 const int* __restrict__ hlen_ptr,
                                                 void* __restrict__ outp) {
    __shared__ char lds[2][16384];   // per buf: [0,8192)=K tile, [8192,16384)=V tile

    const int QT = 8;                             // 256-q tiles
    const int blk = blockIdx.x;
    const int bh  = blk / (QT * SPLITS);
    const int rr  = blk % (QT * SPLITS);
    const int q0  = (rr / SPLITS) << 8;
    const int kq  = rr % SPLITS;
    const int kbase = kq * (S / SPLITS);
    const int NTt   = S / SPLITS / 64;

    const int b    = bh / 12;
    const int t    = threadIdx.x;
    const int w    = t >> 6;                      // 0..7
    const int lane = t & 63;
    const int h    = lane >> 5;
    const int c31  = lane & 31;
    const int hcode = hlen_ptr[0];
    const size_t head = (size_t)bh * S * D;

    // ---- staging source offsets (inverse swizzle on global address) ----
    const int s_  = lane & 7;
    const int r3l = lane >> 3;
    const int e1  = s_ ^ r3l ^ (w & 7);
    const int u1  = e1 ^ ((e1 & 1) << 2);
    const int kgo1 = (8 * w + r3l) * 128 + u1 * 16;
    const int vgo1 = (8 * w + r3l) * 4096 + u1 * 16;
    const char* Kg = (const char*)(Kn + head);   // key-row stride 128 B
    const char* Vg = (const char*)(Vt + head);   // d-row stride 4096 B

    // ---- LDS read offsets per key-half (loop-invariant, wave-independent) ----
    char* ldsc = &lds[0][0];
    int koffs[2][4], voffs[2][2][2];
    #pragma unroll
    for (int kh2 = 0; kh2 < 2; ++kh2) {
        int krow = kh2 * 32 + c31;
        int kb3  = (krow & 7) ^ (krow >> 3) ^ (h << 2) ^ h;
        #pragma unroll
        for (int kd = 0; kd < 4; ++kd)
            koffs[kh2][kd] = krow * 128 + (((2 * kd) ^ kb3)) * 16;
        int vb3 = (c31 & 7) ^ (c31 >> 3) ^ (h << 2) ^ h ^ (kh2 << 2);
        #pragma unroll
        for (int kb2 = 0; kb2 < 2; ++kb2) {
            voffs[kh2][kb2][0] = c31 * 128        + (((kb2 << 1) ^ vb3)) * 16     + 8192;
            voffs[kh2][kb2][1] = (32 + c31) * 128 + (((kb2 << 1) ^ vb3 ^ 4)) * 16 + 8192;
        }
    }

    // ---- fused Q-norm: build B-fragments from raw fp32 Q ----
    // B-frag layout: col = c31 = local q-row, lane h selects d = 16*kd + 8*h + j.
    // Row (q0+w*32+c31) is split across lanes c31 (h=0) and c31+32 (h=1):
    // one shfl_xor(32) completes the row sumsq.
    bf16x8 qf[4];
    {
        const float* qp = Qf + head + (size_t)(q0 + w * 32 + c31) * D + h * 8;
        float4 qa[8];
        float ss = 0.f;
        #pragma unroll
        for (int kd = 0; kd < 4; ++kd) {
            float4 a = *(const float4*)(qp + kd * 16);
            float4 c = *(const float4*)(qp + kd * 16 + 4);
            qa[2 * kd] = a; qa[2 * kd + 1] = c;
            ss += a.x * a.x + a.y * a.y + a.z * a.z + a.w * a.w
                + c.x * c.x + c.y * c.y + c.z * c.z + c.w * c.w;
        }
        ss += __shfl_xor(ss, 32, 64);
        float sc = rsqrtf(ss + 1e-6f);
        #pragma unroll
        for (int kd = 0; kd < 4; ++kd) {
            union { int i[4]; bf16x8 v; } qq;
            float4 a = qa[2 * kd], c = qa[2 * kd + 1];
            qq.i[0] = cvtpk_bf16(a.x * sc, a.y * sc);
            qq.i[1] = cvtpk_bf16(a.z * sc, a.w * sc);
            qq.i[2] = cvtpk_bf16(c.x * sc, c.y * sc);
            qq.i[3] = cvtpk_bf16(c.z * sc, c.w * sc);
            qf[kd] = qq.v;
        }
    }
    asm volatile("" :: "v"(qf[0]), "v"(qf[1]), "v"(qf[2]), "v"(qf[3]));

    const f32x16 z16 = {0,0,0,0,0,0,0,0,0,0,0,0,0,0,0,0};
    f32x16 xacc0 = z16, xacc1 = z16;

    const bool  p9 = (hcode == 9);
    const float hf = (float)hcode;

    // packed fp16 constants (native vector ops -> v_pk_*_f16)
    const h2v one2  = {(_Float16)1.0f,  (_Float16)1.0f};
    const h2v half2 = {(_Float16)0.5f,  (_Float16)0.5f};
    const h2v zero2 = {(_Float16)0.0f,  (_Float16)0.0f};
    const h2v q3c = {(_Float16)-0.00596128f, (_Float16)-0.00596128f};
    const h2v q2c = {(_Float16)-0.00575336f, (_Float16)-0.00575336f};
    const h2v q1c = {(_Float16)-0.03812704f, (_Float16)-0.03812704f};
    const h2v q0c = {(_Float16)-0.4501324f,  (_Float16)-0.4501324f};

    auto STAGE = [&](int base, int k0) {
        const char* kb = Kg + (size_t)k0 * 128;
        const char* vb = Vg + (size_t)k0 * 2;
        char* Kl = ldsc + base;
        char* Vl = Kl + 8192;
        GLOAD16(kb + kgo1, Kl + w * 1024);        // 512 thr x 16B = full 8KB K tile
        GLOAD16(vb + vgo1, Vl + w * 1024);        // full 8KB V tile
    };

    // generic-hcode scalar fallback
    auto XFgen = [&](float s) -> float {
        float z  = fmaxf(1.0f - fabsf(s), 0.0f);
        float qp = ((0.00596128f * z + 0.00575336f) * z + 0.03812704f) * z + 0.4501324f;
        float tp = 0.5f - __builtin_amdgcn_sqrtf(z) * qp;
        float x  = 0.5f + __builtin_copysignf(tp, s);
        return __builtin_amdgcn_exp2f(hf * __builtin_amdgcn_logf(x));
    };

    auto COMPUTE = [&](int bufbase) {
        const char* base = ldsc + bufbase;
        #pragma unroll
        for (int kh2 = 0; kh2 < 2; ++kh2) {
            // S^T = K_half @ Q^T : C[row=key][col=q]
            __builtin_amdgcn_s_setprio(1);
            f32x16 sacc = __builtin_amdgcn_mfma_f32_32x32x16_bf16(
                *(const bf16x8*)(base + koffs[kh2][0]), qf[0], z16, 0, 0, 0);
            #pragma unroll
            for (int kd = 1; kd < 4; ++kd)
                sacc = __builtin_amdgcn_mfma_f32_32x32x16_bf16(
                    *(const bf16x8*)(base + koffs[kh2][kd]), qf[kd], sacc, 0, 0, 0);
            __builtin_amdgcn_s_setprio(0);

            // w = x^h, x = 0.5 + copysign(0.5 - sqrt(z)*q(z), s), z = 1-|s|
            // packed fp16: 2 elems per op, sign bits ride along in the pack.
            int u_[8];
            union HU { h2v v; fp16x2 p; uint32 u; };
            if (p9) {
                #pragma unroll
                for (int i = 0; i < 8; ++i) {
                    HU cv; cv.p = __builtin_amdgcn_cvt_pkrtz(sacc[2 * i], sacc[2 * i + 1]);
                    uint32 spb = cv.u;
                    HU za; za.u = spb & 0x7FFF7FFFu;                 // |s|
                    h2v z = one2 - za.v;
                    z = __builtin_elementwise_max(z, zero2);          // max(1-|s|,0)
                    h2v rt = __builtin_elementwise_sqrt(z);
                    h2v q = q3c * z + q2c;                            // -q(z) Horner
                    q = q * z + q1c;
                    q = q * z + q0c;
                    HU tb; tb.v = q * rt + half2;                     // 0.5 - q(z)*sqrt(z) >= 0
                    HU xb; xb.u = (tb.u & 0x7FFF7FFFu) | (spb & 0x80008000u);
                    h2v x = xb.v + half2;                             // 0.5 + copysign(tp, s)
                    h2v x2 = x * x;
                    h2v x4 = x2 * x2;
                    h2v x8 = x4 * x4;
                    HU wr; wr.v = x8 * x;                             // x^9, packed fp16
                    u_[i] = (int)wr.u;
                }
            } else {
                #pragma unroll
                for (int i = 0; i < 8; ++i) {
                    HU cv;
                    cv.p = __builtin_amdgcn_cvt_pkrtz(XFgen(sacc[2 * i]),
                                                      XFgen(sacc[2 * i + 1]));
                    u_[i] = (int)cv.u;
                }
            }
            asm("v_permlane32_swap_b32 %0, %1" : "+v"(u_[0]), "+v"(u_[2]));
            asm("v_permlane32_swap_b32 %0, %1" : "+v"(u_[1]), "+v"(u_[3]));
            asm("v_permlane32_swap_b32 %0, %1" : "+v"(u_[4]), "+v"(u_[6]));
            asm("v_permlane32_swap_b32 %0, %1" : "+v"(u_[5]), "+v"(u_[7]));
            union { int i[4]; h8 v; } f0, f1;
            f0.i[0] = u_[0]; f0.i[1] = u_[1]; f0.i[2] = u_[2]; f0.i[3] = u_[3];
            f1.i[0] = u_[4]; f1.i[1] = u_[5]; f1.i[2] = u_[6]; f1.i[3] = u_[7];

            // X += P_half @ V_half (fp16 MFMA; fragment layout dtype-independent)
            h8 vf00 = *(const h8*)(base + voffs[kh2][0][0]);
            h8 vf01 = *(const h8*)(base + voffs[kh2][0][1]);
            h8 vf10 = *(const h8*)(base + voffs[kh2][1][0]);
            h8 vf11 = *(const h8*)(base + voffs[kh2][1][1]);
            __builtin_amdgcn_s_setprio(1);
            xacc0 = __builtin_amdgcn_mfma_f32_32x32x16_f16(f0.v, vf00, xacc0, 0, 0, 0);
            xacc1 = __builtin_amdgcn_mfma_f32_32x32x16_f16(f0.v, vf01, xacc1, 0, 0, 0);
            xacc0 = __builtin_amdgcn_mfma_f32_32x32x16_f16(f1.v, vf10, xacc0, 0, 0, 0);
            xacc1 = __builtin_amdgcn_mfma_f32_32x32x16_f16(f1.v, vf11, xacc1, 0, 0, 0);
            __builtin_amdgcn_s_setprio(0);
        }
    };

    // ---- main loop: drain -> barrier -> stage-next -> compute ----
    STAGE(0, kbase);
    for (int t2 = 0; t2 < NTt; ++t2) {
        asm volatile("s_waitcnt vmcnt(0)" ::: "memory");
        __builtin_amdgcn_s_barrier();
        if (t2 + 1 < NTt) STAGE(((t2 + 1) & 1) * 16384, kbase + (t2 + 1) * 64);
        COMPUTE((t2 & 1) * 16384);
    }

    // epilogue: per-wave complete 32x64 output
    #pragma unroll
    for (int r = 0; r < 16; ++r) {
        int q  = (r & 3) + 8 * (r >> 2) + 4 * h;
        int qg = q0 + w * 32 + q;
        if (SPLITS > 1) {
            __half* pp = (__half*)outp + ((size_t)(kq * NBH + bh) * S + qg) * D;
            pp[c31]      = __float2half(xacc0[r]);
            pp[32 + c31] = __float2half(xacc1[r]);
        } else {
            float mq = (float)mask[b * S + qg];
            float x0 = xacc0[r] * mq, x1 = xacc1[r] * mq;
            float ss = x0 * x0 + x1 * x1;
            #pragma unroll
            for (int m = 1; m <= 16; m <<= 1) ss += __shfl_xor(ss, m, 64);
            float sc = rsqrtf(ss + 1e-6f);
            float* op = (float*)outp + ((size_t)bh * S + qg) * D;
            op[c31]      = x0 * sc;
            op[32 + c31] = x1 * sc;
        }
    }
}

// Pass 2: sum fp16 key-split partials, query mask, L2-normalize, fp32 out.
template<int SPLITS>
__global__ __launch_bounds__(256) void combine_norm(const __half* __restrict__ P,
                                                    const int* __restrict__ mask,
                                                    float* __restrict__ out) {
    int t = threadIdx.x;
    int l16 = t & 15;
    size_t row = (size_t)blockIdx.x * 16 + (t >> 4);
    size_t i = row * 64 + l16 * 4;
    float x0 = 0.f, x1 = 0.f, x2 = 0.f, x3 = 0.f;
    #pragma unroll
    for (int k = 0; k < SPLITS; ++k) {
        const __half2* p2 = (const __half2*)(P + (size_t)k * NBH * S * D + i);
        __half2 ab = p2[0], cd = p2[1];
        x0 += __low2float(ab); x1 += __high2float(ab);
        x2 += __low2float(cd); x3 += __high2float(cd);
    }
    int bh = (int)(row >> 11);
    int sidx = (int)(row & 2047);
    int b = bh / 12;
    float mq = (float)mask[b * S + sidx];
    x0 *= mq; x1 *= mq; x2 *= mq; x3 *= mq;
    float ss = x0 * x0 + x1 * x1 + x2 * x2 + x3 * x3;
    #pragma unroll
    for (int m = 1; m <= 8; m <<= 1) ss += __shfl_xor(ss, m, 64);
    float sc = rsqrtf(ss + 1e-6f);
    float4 o = { x0 * sc, x1 * sc, x2 * sc, x3 * sc };
    *(float4*)(out + i) = o;
}

extern "C" void kernel_launch(void* const* d_in, const int* in_sizes, int n_in,
                              void* d_out, int out_size, void* d_ws, size_t ws_size,
                              hipStream_t stream) {
    const float* Q    = (const float*)d_in[0];
    const float* K    = (const float*)d_in[1];
    const float* V    = (const float*)d_in[2];
    const int*   mask = (const int*)d_in[3];
    const int*   hlen = (const int*)d_in[4];
    float*       out  = (float*)d_out;

    __hip_bfloat16* Kn = (__hip_bfloat16*)d_ws;
    __half*         Vt = (__half*)(Kn + (size_t)NBH * S * D);
    __half* Pbuf = (__half*)((char*)d_ws + 2ull * NBH * S * D * 2);  // fp16 partials

    const size_t base_b = 2ull * NBH * S * D * 2;    // Kn + Vt (12.6 MB)
    const size_t part_h = (size_t)NBH * S * D * 2;   // one fp16 partial buffer

    prep<<<NBH * S / 16 + NBH * 32, 256, 0, stream>>>(K, V, mask, Kn, Vt);
    if (ws_size >= base_b + 4 * part_h) {            // 37.8 MB (within proven budget)
        yoso_main<4><<<NBH * 8 * 4, 512, 0, stream>>>(Q, Kn, Vt, mask, hlen, Pbuf);
        combine_norm<4><<<NBH * S / 16, 256, 0, stream>>>(Pbuf, mask, out);
    } else if (ws_size >= base_b + 2 * part_h) {
        yoso_main<2><<<NBH * 8 * 2, 512, 0, stream>>>(Q, Kn, Vt, mask, hlen, Pbuf);
        combine_norm<2><<<NBH * S / 16, 256, 0, stream>>>(Pbuf, mask, out);
    } else {
        yoso_main<1><<<NBH * 8, 512, 0, stream>>>(Q, Kn, Vt, mask, hlen, out);
    }
}